// Round 6
// baseline (500.276 us; speedup 1.0000x reference)
//
#include <hip/hip_runtime.h>
#include <hip/hip_bf16.h>

#define SCALE_F 0.125f

typedef __attribute__((ext_vector_type(8))) short short8;
typedef __attribute__((ext_vector_type(4))) float f32x4;

__device__ __forceinline__ unsigned short f2b(float f){
  unsigned int x = __float_as_uint(f);
  return (unsigned short)((x + 0x7fffu + ((x >> 16) & 1u)) >> 16);
}
__device__ __forceinline__ float b2f(unsigned short h){
  return __uint_as_float((unsigned int)h << 16);
}

// Transpose-cast W [512k,512n] f32 -> WT [n][k] bf16 (z picks which W).
__global__ __launch_bounds__(256)
void wcast_t(const float* __restrict__ W0, unsigned short* __restrict__ T0,
             const float* __restrict__ W1, unsigned short* __restrict__ T1)
{
  __shared__ unsigned short tile[64][72];
  const float* W = blockIdx.z ? W1 : W0;
  unsigned short* T = blockIdx.z ? T1 : T0;
  int k0 = blockIdx.x * 64, n0 = blockIdx.y * 64;
  #pragma unroll
  for (int j = 0; j < 16; j++) {
    int idx = threadIdx.x + j * 256;
    int r = idx >> 6, c = idx & 63;
    tile[r][c] = f2b(W[(size_t)(k0 + r) * 512 + n0 + c]);
  }
  __syncthreads();
  #pragma unroll
  for (int j = 0; j < 16; j++) {
    int idx = threadIdx.x + j * 256;
    int r = idx >> 6, c = idx & 63;
    T[(size_t)(n0 + r) * 512 + k0 + c] = tile[c][r];
  }
}

// Small-M MFMA GEMM with bf16x3 split (f32-class accuracy).
// MODE 0: plain f32 out [M,512]
// MODE 1: K=1024; k>=512 rows of A come from p0+p1 (summed in staging)
// MODE 2: Q-layout out [b,h,512,64], scaled
// MODE 3: S-layout out [b,h,32,64]
template<int MODE>
__global__ __launch_bounds__(256)
void sgemm_mfma(const float* __restrict__ A0, const float* __restrict__ A1,
                const float* __restrict__ p0, const float* __restrict__ p1,
                const float* __restrict__ W0, const float* __restrict__ W1,
                const float* __restrict__ bias0, const float* __restrict__ bias1,
                float* __restrict__ out0, float* __restrict__ out1,
                float scale, int M, int K)
{
  __shared__ unsigned short Ah[4096], Al[4096], Bh[4096], Bl[4096];
  const int z = blockIdx.z;
  const float* A    = z ? A1 : A0;
  const float* W    = z ? W1 : W0;
  const float* bias = z ? bias1 : bias0;
  float* outf       = z ? out1 : out0;

  const int m0 = blockIdx.x * 64, n0 = blockIdx.y * 64;
  const int tid = threadIdx.x;
  const int lane = tid & 63, wv = tid >> 6, lr = lane & 15, lg = lane >> 4;

  f32x4 acc[4];
  #pragma unroll
  for (int nf = 0; nf < 4; nf++) acc[nf] = (f32x4){0.f, 0.f, 0.f, 0.f};

  for (int k0 = 0; k0 < K; k0 += 64) {
    float4 a0[2], a1[2];
    float bw[2][8];
    const bool dual = (MODE == 1) && (k0 >= 512);
    const int kk = dual ? (k0 - 512) : k0;
    #pragma unroll
    for (int j = 0; j < 2; j++) {
      int idx = tid + j * 256;
      int row = idx >> 3, c8 = idx & 7;
      size_t base = (size_t)(m0 + row) * 512 + kk + c8 * 8;
      if (dual) {
        float4 x0 = *(const float4*)&p0[base];
        float4 x1 = *(const float4*)&p0[base + 4];
        float4 y0 = *(const float4*)&p1[base];
        float4 y1 = *(const float4*)&p1[base + 4];
        a0[j] = (float4){x0.x + y0.x, x0.y + y0.y, x0.z + y0.z, x0.w + y0.w};
        a1[j] = (float4){x1.x + y1.x, x1.y + y1.y, x1.z + y1.z, x1.w + y1.w};
      } else {
        a0[j] = *(const float4*)&A[base];
        a1[j] = *(const float4*)&A[base + 4];
      }
    }
    #pragma unroll
    for (int j = 0; j < 2; j++) {
      int idx = tid + j * 256;
      int nl = idx >> 3, kseg = idx & 7;
      #pragma unroll
      for (int e = 0; e < 8; e++)
        bw[j][e] = W[(size_t)(k0 + kseg * 8 + e) * 512 + n0 + nl];
    }
    __syncthreads();
    #pragma unroll
    for (int j = 0; j < 2; j++) {
      int idx = tid + j * 256;
      int row = idx >> 3, c8 = idx & 7;
      int off = row * 64 + ((c8 * 8) ^ ((row & 7) << 3));
      float v[8] = {a0[j].x, a0[j].y, a0[j].z, a0[j].w,
                    a1[j].x, a1[j].y, a1[j].z, a1[j].w};
      short8 h, l;
      #pragma unroll
      for (int e = 0; e < 8; e++) {
        unsigned short hh = f2b(v[e]);
        h[e] = (short)hh;
        l[e] = (short)f2b(v[e] - b2f(hh));
      }
      *(short8*)&Ah[off] = h;
      *(short8*)&Al[off] = l;
    }
    #pragma unroll
    for (int j = 0; j < 2; j++) {
      int idx = tid + j * 256;
      int nl = idx >> 3, kseg = idx & 7;
      int off = nl * 64 + ((kseg * 8) ^ ((nl & 7) << 3));
      short8 h, l;
      #pragma unroll
      for (int e = 0; e < 8; e++) {
        unsigned short hh = f2b(bw[j][e]);
        h[e] = (short)hh;
        l[e] = (short)f2b(bw[j][e] - b2f(hh));
      }
      *(short8*)&Bh[off] = h;
      *(short8*)&Bl[off] = l;
    }
    __syncthreads();
    #pragma unroll
    for (int ks = 0; ks < 2; ks++) {
      int rowa = wv * 16 + lr;
      int aoff = rowa * 64 + ((ks * 32 + lg * 8) ^ ((rowa & 7) << 3));
      short8 ah = *(const short8*)&Ah[aoff];
      short8 al = *(const short8*)&Al[aoff];
      #pragma unroll
      for (int nf = 0; nf < 4; nf++) {
        int rowb = nf * 16 + lr;
        int boff = rowb * 64 + ((ks * 32 + lg * 8) ^ ((rowb & 7) << 3));
        short8 bh = *(const short8*)&Bh[boff];
        short8 bl = *(const short8*)&Bl[boff];
        acc[nf] = __builtin_amdgcn_mfma_f32_16x16x32_bf16(ah, bh, acc[nf], 0, 0, 0);
        acc[nf] = __builtin_amdgcn_mfma_f32_16x16x32_bf16(ah, bl, acc[nf], 0, 0, 0);
        acc[nf] = __builtin_amdgcn_mfma_f32_16x16x32_bf16(al, bh, acc[nf], 0, 0, 0);
      }
    }
  }

  #pragma unroll
  for (int nf = 0; nf < 4; nf++) {
    int n = n0 + nf * 16 + lr;
    float bv = bias[n];
    #pragma unroll
    for (int i = 0; i < 4; i++) {
      int m = m0 + wv * 16 + lg * 4 + i;
      float v = (acc[nf][i] + bv) * scale;
      if (MODE == 0 || MODE == 1) {
        outf[(size_t)m * 512 + n] = v;
      } else if (MODE == 2) {
        int bb = m >> 9, qq = m & 511, hh = n >> 6, d = n & 63;
        outf[((((size_t)bb * 8 + hh) * 512 + qq) << 6) + d] = v;
      } else {
        int bb = m >> 5, nn = m & 31, hh = n >> 6, d = n & 63;
        outf[((((size_t)bb * 8 + hh) * 32 + nn) << 6) + d] = v;
      }
    }
  }
}

// MFMA projection GEMM, tile 128x128, BK=64, 4 waves x 64x64.
// VT=0: out bf16 [b,h,n,t(256),d(64)]  (K path, row-major in d)
// VT=1: out bf16 [b,h,n,d(64),t(256)]  (V path, TRANSPOSED: rows of t per d)
template<int VT>
__global__ __launch_bounds__(256)
void proj_gemm(const float* __restrict__ A,          // [32768,512] f32
               const unsigned short* __restrict__ BT,// [512n][512k] bf16
               const float* __restrict__ bias,       // [512]
               __hip_bfloat16* __restrict__ outW)
{
  __shared__ unsigned short As[128 * 64];
  __shared__ unsigned short Bs[128 * 64];
  const int m0 = blockIdx.x * 128, n0 = blockIdx.y * 128;
  const int tid = threadIdx.x;
  const int lane = tid & 63, wv = tid >> 6, lr = lane & 15, lg = lane >> 4;
  const int wr = wv >> 1, wc = wv & 1;

  f32x4 acc[4][4];
  #pragma unroll
  for (int mi = 0; mi < 4; mi++)
    #pragma unroll
    for (int nj = 0; nj < 4; nj++) acc[mi][nj] = (f32x4){0.f, 0.f, 0.f, 0.f};

  for (int k0 = 0; k0 < 512; k0 += 64) {
    float4 a0[4], a1[4]; uint4 bq[4];
    #pragma unroll
    for (int j = 0; j < 4; j++) {
      int idx = tid + j * 256;
      int row = idx >> 3, c8 = idx & 7;
      const float* ap = A + (size_t)(m0 + row) * 512 + k0 + c8 * 8;
      a0[j] = *(const float4*)ap;
      a1[j] = *(const float4*)(ap + 4);
      bq[j] = *(const uint4*)(BT + (size_t)(n0 + row) * 512 + k0 + c8 * 8);
    }
    __syncthreads();
    #pragma unroll
    for (int j = 0; j < 4; j++) {
      int idx = tid + j * 256;
      int row = idx >> 3, c8 = idx & 7;
      int off = row * 64 + ((c8 * 8) ^ ((row & 7) << 3));
      short8 pk;
      pk[0] = (short)f2b(a0[j].x); pk[1] = (short)f2b(a0[j].y);
      pk[2] = (short)f2b(a0[j].z); pk[3] = (short)f2b(a0[j].w);
      pk[4] = (short)f2b(a1[j].x); pk[5] = (short)f2b(a1[j].y);
      pk[6] = (short)f2b(a1[j].z); pk[7] = (short)f2b(a1[j].w);
      *(short8*)&As[off] = pk;
      *(uint4*)&Bs[off] = bq[j];
    }
    __syncthreads();
    #pragma unroll
    for (int ks = 0; ks < 2; ks++) {
      short8 af[4], bfp[4];
      #pragma unroll
      for (int mi = 0; mi < 4; mi++) {
        int row = wr * 64 + mi * 16 + lr;
        af[mi] = *(const short8*)&As[row * 64 + ((ks * 32 + lg * 8) ^ ((row & 7) << 3))];
      }
      #pragma unroll
      for (int nj = 0; nj < 4; nj++) {
        int row = wc * 64 + nj * 16 + lr;
        bfp[nj] = *(const short8*)&Bs[row * 64 + ((ks * 32 + lg * 8) ^ ((row & 7) << 3))];
      }
      #pragma unroll
      for (int mi = 0; mi < 4; mi++)
        #pragma unroll
        for (int nj = 0; nj < 4; nj++)
          acc[mi][nj] = __builtin_amdgcn_mfma_f32_16x16x32_bf16(af[mi], bfp[nj], acc[mi][nj], 0, 0, 0);
    }
  }

  #pragma unroll
  for (int nj = 0; nj < 4; nj++) {
    int n = n0 + wc * 64 + nj * 16 + lr;
    float bv = bias[n];
    int hh = n >> 6, d = n & 63;
    #pragma unroll
    for (int mi = 0; mi < 4; mi++) {
      if (VT == 0) {
        #pragma unroll
        for (int i = 0; i < 4; i++) {
          int m = m0 + wr * 64 + mi * 16 + lg * 4 + i;
          int bb = m >> 13, r = m & 8191, nn = r >> 8, tt = r & 255;
          outW[(((((size_t)bb * 8 + hh) * 32 + nn) * 256 + tt) << 6) + d] =
              __float2bfloat16(acc[mi][nj][i] + bv);
        }
      } else {
        int m = m0 + wr * 64 + mi * 16 + lg * 4;   // 4 consecutive t
        int bb = m >> 13, r = m & 8191, nn = r >> 8, t0 = r & 255;
        uint2 pk;
        pk.x = (unsigned)f2b(acc[mi][nj][0] + bv) | ((unsigned)f2b(acc[mi][nj][1] + bv) << 16);
        pk.y = (unsigned)f2b(acc[mi][nj][2] + bv) | ((unsigned)f2b(acc[mi][nj][3] + bv) << 16);
        *(uint2*)((unsigned short*)outW +
                  (((((size_t)bb * 8 + hh) * 32 + nn) * 64 + d) << 8) + t0) = pk;
      }
    }
  }
}

// Sentence-level attention: scores over nb=32, softmax, ctx_s; also emits attn_s.
__global__ __launch_bounds__(256)
void sent_attn(const float* __restrict__ qs,   // [b,h,512,64]  (pre-scaled)
               const float* __restrict__ ks,   // [b,h,32,64]
               const float* __restrict__ vs,   // [b,h,32,64]
               float* __restrict__ attn_s,     // [b,h,512,32]
               float* __restrict__ ctx_s)      // [b,512,512]
{
  __shared__ float qsS[32][68];
  __shared__ float ksS[32][68];
  __shared__ float vsS[32][68];
  __shared__ float sS[32][36];
  const int bh = blockIdx.y, b = bh >> 3, h = bh & 7;
  const int q0 = blockIdx.x * 32;
  const int tid = threadIdx.x;

  #pragma unroll
  for (int i = 0; i < 2; i++) {
    int idx = tid + i * 256;
    int r = idx >> 4, c = (idx & 15) * 4;
    *(float4*)&qsS[r][c] = *(const float4*)&qs[((size_t)bh * 512 + q0 + r) * 64 + c];
    *(float4*)&ksS[r][c] = *(const float4*)&ks[((size_t)bh * 32 + r) * 64 + c];
    *(float4*)&vsS[r][c] = *(const float4*)&vs[((size_t)bh * 32 + r) * 64 + c];
  }
  __syncthreads();

  #pragma unroll
  for (int it = 0; it < 4; it++) {
    int pair = tid + it * 256;
    int qq = pair >> 5, nn = pair & 31;
    float s = 0.f;
    #pragma unroll
    for (int k = 0; k < 64; k++) s += qsS[qq][k] * ksS[nn][k];
    sS[qq][nn] = s;
  }
  __syncthreads();

  if (tid < 32) {
    int qq = tid;
    float m = -1e30f;
    #pragma unroll
    for (int n = 0; n < 32; n++) m = fmaxf(m, sS[qq][n]);
    float p[32];
    float sum = 0.f;
    #pragma unroll
    for (int n = 0; n < 32; n++) { p[n] = __expf(sS[qq][n] - m); sum += p[n]; }
    float inv = 1.f / sum;
    #pragma unroll
    for (int n = 0; n < 32; n++) {
      float pv = p[n] * inv;
      sS[qq][n] = pv;
      attn_s[((size_t)bh * 512 + q0 + qq) * 32 + n] = pv;
    }
  }
  __syncthreads();

  #pragma unroll
  for (int it = 0; it < 8; it++) {
    int idx = tid + it * 256;
    int qq = idx >> 6, d = idx & 63;
    float c = 0.f;
    #pragma unroll
    for (int n = 0; n < 32; n++) c += sS[qq][n] * vsS[n][d];
    ctx_s[((size_t)b * 512 + q0 + qq) * 512 + h * 64 + d] = c;
  }
}

// Token-level attention v2: no K/V LDS staging (direct L2 reads), no barriers.
// 512 blocks 1D, XCD-grouped: bid&7 = XCD, 4 bh per XCD (16 blocks per bh
// co-resident on one XCD -> K/V L2-hits). 4 waves x 16 q-rows per block.
// pbuf is wave-private (rows wv*16..+15): only lgkmcnt ordering needed.
__global__ __launch_bounds__(256, 3)
void tok_attn_v2(const float* __restrict__ qw,            // [b,h,512,64] f32 pre-scaled
                 const __hip_bfloat16* __restrict__ kw,   // [b,h,32,256,64]
                 const __hip_bfloat16* __restrict__ vwT,  // [b,h,32,64,256] TRANSPOSED
                 const float* __restrict__ attn_s,        // [b,h,512,32]
                 float* __restrict__ part0,
                 float* __restrict__ part1)
{
  __shared__ unsigned short pbuf[64 * 264];  // P as [64 q-rows][256 t + 8 pad]
  const int bid = blockIdx.x;
  const int xcd = bid & 7, slot = bid >> 3;
  const int bh = xcd * 4 + (slot >> 4);
  const int rest = slot & 15;
  const int qt = rest >> 1, z = rest & 1;
  const int b = bh >> 3, h = bh & 7;
  const int tid = threadIdx.x;
  const int wv = tid >> 6, lane = tid & 63, lg = lane >> 4, lr = lane & 15;
  const int qbase = qt * 64 + wv * 16;
  const int n0 = z * 16;

  short8 qfrag[2];
  {
    const float* qrow = qw + ((size_t)bh * 512 + qbase + lr) * 64;
    #pragma unroll
    for (int ks = 0; ks < 2; ks++) {
      float4 u0 = *(const float4*)&qrow[ks * 32 + lg * 8];
      float4 u1 = *(const float4*)&qrow[ks * 32 + lg * 8 + 4];
      short8 t;
      t[0] = f2b(u0.x); t[1] = f2b(u0.y); t[2] = f2b(u0.z); t[3] = f2b(u0.w);
      t[4] = f2b(u1.x); t[5] = f2b(u1.y); t[6] = f2b(u1.z); t[7] = f2b(u1.w);
      qfrag[ks] = t;
    }
  }

  f32x4 acc[4];
  #pragma unroll
  for (int dt = 0; dt < 4; dt++) acc[dt] = (f32x4){0.f, 0.f, 0.f, 0.f};

  const unsigned short* kwb = (const unsigned short*)kw + (size_t)bh * 32 * 256 * 64;
  const unsigned short* vtb = (const unsigned short*)vwT + (size_t)bh * 32 * 64 * 256;
  const float* asrow = attn_s + ((size_t)bh * 512 + qbase + lr) * 32;
  const unsigned int pbase = (wv * 16 + lr) * 264;

  for (int ni = 0; ni < 16; ni++) {
    const int n = n0 + ni;
    const float asn = asrow[n];

    // QK: A-frags straight from global (L2-resident after XCD grouping)
    f32x4 sfr[16];
    #pragma unroll
    for (int tt = 0; tt < 16; tt++) sfr[tt] = (f32x4){0.f, 0.f, 0.f, 0.f};
    const unsigned short* krow = kwb + ((size_t)n * 256) * 64;
    #pragma unroll
    for (int tt = 0; tt < 16; tt++) {
      const unsigned short* kp = krow + (tt * 16 + lr) * 64 + lg * 8;
      short8 kf0 = *(const short8*)kp;
      short8 kf1 = *(const short8*)(kp + 32);
      sfr[tt] = __builtin_amdgcn_mfma_f32_16x16x32_bf16(kf0, qfrag[0], sfr[tt], 0, 0, 0);
      sfr[tt] = __builtin_amdgcn_mfma_f32_16x16x32_bf16(kf1, qfrag[1], sfr[tt], 0, 0, 0);
    }

    // softmax (shift-free) + sentence weighting for q = qbase+lr
    float lsum = 0.f;
    #pragma unroll
    for (int tt = 0; tt < 16; tt++) {
      #pragma unroll
      for (int i = 0; i < 4; i++) {
        float e = __expf(sfr[tt][i]);
        sfr[tt][i] = e;
        lsum += e;
      }
    }
    lsum += __shfl_xor(lsum, 16);
    lsum += __shfl_xor(lsum, 32);
    const float coef = asn / lsum;

    #pragma unroll
    for (int tt = 0; tt < 16; tt++) {
      uint2 pk;
      pk.x = (unsigned)f2b(sfr[tt][0] * coef) | ((unsigned)f2b(sfr[tt][1] * coef) << 16);
      pk.y = (unsigned)f2b(sfr[tt][2] * coef) | ((unsigned)f2b(sfr[tt][3] * coef) << 16);
      *(uint2*)&pbuf[pbase + tt * 16 + lg * 4] = pk;
    }
    asm volatile("s_waitcnt lgkmcnt(0)" ::: "memory");

    // PV: A from wave-private pbuf, B straight from transposed global V
    const unsigned short* vrow = vtb + ((size_t)n * 64) * 256;
    #pragma unroll
    for (int ks = 0; ks < 8; ks++) {
      short8 pa = *(const short8*)&pbuf[pbase + ks * 32 + lg * 8];
      #pragma unroll
      for (int dt = 0; dt < 4; dt++) {
        short8 vb = *(const short8*)(vrow + (dt * 16 + lr) * 256 + ks * 32 + lg * 8);
        acc[dt] = __builtin_amdgcn_mfma_f32_16x16x32_bf16(pa, vb, acc[dt], 0, 0, 0);
      }
    }
  }

  float* pout = z ? part1 : part0;
  #pragma unroll
  for (int dt = 0; dt < 4; dt++) {
    #pragma unroll
    for (int i = 0; i < 4; i++) {
      int qg = qt * 64 + wv * 16 + lg * 4 + i;
      pout[((size_t)b * 512 + qg) * 512 + h * 64 + dt * 16 + lr] = acc[dt][i];
    }
  }
}

extern "C" void kernel_launch(void* const* d_in, const int* in_sizes, int n_in,
                              void* d_out, int out_size, void* d_ws, size_t ws_size,
                              hipStream_t stream)
{
  (void)in_sizes; (void)n_in; (void)out_size; (void)ws_size;
  const float* q    = (const float*)d_in[0];
  const float* k_w  = (const float*)d_in[1];
  const float* v_w  = (const float*)d_in[2];
  const float* k_s  = (const float*)d_in[3];
  const float* v_s  = (const float*)d_in[4];
  const float* W_qs = (const float*)d_in[5];  const float* b_qs = (const float*)d_in[6];
  const float* W_ks = (const float*)d_in[7];  const float* b_ks = (const float*)d_in[8];
  const float* W_vs = (const float*)d_in[9];  const float* b_vs = (const float*)d_in[10];
  const float* W_qw = (const float*)d_in[11]; const float* b_qw = (const float*)d_in[12];
  const float* W_kw = (const float*)d_in[13]; const float* b_kw = (const float*)d_in[14];
  const float* W_vw = (const float*)d_in[15]; const float* b_vw = (const float*)d_in[16];
  const float* W_fc1= (const float*)d_in[17]; const float* b_fc1= (const float*)d_in[18];
  const float* W_fc = (const float*)d_in[19]; const float* b_fc = (const float*)d_in[20];
  float* out = (float*)d_out;

  char* ws = (char*)d_ws;
  const size_t MB = 1ull << 20;
  const size_t KB = 1ull << 10;
  float* qs_ws    = (float*)(ws + 0 * MB);       // [b,h,512,64] 4 MB (dead after sent_attn)
  float* qw_ws    = (float*)(ws + 4 * MB);       // [b,h,512,64] 4 MB
  float* ks_ws    = (float*)(ws + 8 * MB);       // [b,h,32,64] 256 KB
  unsigned short* WkT = (unsigned short*)(ws + 8 * MB + 512 * KB);  // 512 KB
  float* vs_ws    = (float*)(ws + 9 * MB);       // [b,h,32,64] 256 KB
  unsigned short* WvT = (unsigned short*)(ws + 9 * MB + 512 * KB);  // 512 KB
  float* attns_ws = (float*)(ws + 10 * MB);      // [b,h,512,32] 2 MB
  float* ctxs_ws  = (float*)(ws + 12 * MB);      // [b,512,512] 4 MB (dead after fc1 gemm)
  float* ctxsf_ws = (float*)(ws + 16 * MB);      // [b,512,512] 4 MB
  __hip_bfloat16* kw_ws  = (__hip_bfloat16*)(ws + 24 * MB);  // [b,h,32,256,64] 32 MB
  __hip_bfloat16* vwT_ws = (__hip_bfloat16*)(ws + 56 * MB);  // [b,h,32,64,256] 32 MB
  float* part0 = (float*)(ws + 0 * MB);          // over qs_ws   (4 MB)
  float* part1 = (float*)(ws + 12 * MB);         // over ctxs_ws (4 MB)

  dim3 blk(256);
  // weight transpose-casts for the MFMA projections
  wcast_t<<<dim3(8, 8, 2), blk, 0, stream>>>(W_kw, WkT, W_vw, WvT);
  // small projections (MFMA, bf16x3 split): qs+qw fused, ks+vs fused
  sgemm_mfma<2><<<dim3(32, 8, 2), blk, 0, stream>>>(
      q, q, nullptr, nullptr, W_qs, W_qw, b_qs, b_qw, qs_ws, qw_ws, SCALE_F, 2048, 512);
  sgemm_mfma<3><<<dim3(2, 8, 2), blk, 0, stream>>>(
      k_s, v_s, nullptr, nullptr, W_ks, W_vs, b_ks, b_vs, ks_ws, vs_ws, 1.f, 128, 512);
  // big projections (MFMA): K row-major, V transposed for direct PV B-frag reads
  proj_gemm<0><<<dim3(256, 4), blk, 0, stream>>>(k_w, WkT, b_kw, kw_ws);
  proj_gemm<1><<<dim3(256, 4), blk, 0, stream>>>(v_w, WvT, b_vw, vwT_ws);
  // sentence attention (+ attn_s for token level)
  sent_attn<<<dim3(16, 32), blk, 0, stream>>>(qs_ws, ks_ws, vs_ws, attns_ws, ctxs_ws);
  // ctx_s @ W_fc1
  sgemm_mfma<0><<<dim3(32, 8, 1), blk, 0, stream>>>(
      ctxs_ws, ctxs_ws, nullptr, nullptr, W_fc1, W_fc1, b_fc1, b_fc1,
      ctxsf_ws, ctxsf_ws, 1.f, 2048, 512);
  // token attention v2 (no staging, XCD-grouped) -> partials
  tok_attn_v2<<<dim3(512), blk, 0, stream>>>(qw_ws, kw_ws, vwT_ws, attns_ws, part0, part1);
  // final combine: concat([ctx_s_fc1, part0+part1]) @ W_fc + b_fc
  sgemm_mfma<1><<<dim3(32, 8, 1), blk, 0, stream>>>(
      ctxsf_ws, ctxsf_ws, part0, part1, W_fc, W_fc, b_fc, b_fc,
      out, out, 1.f, 2048, 1024);
}

// Round 7
// 460.431 us; speedup vs baseline: 1.0865x; 1.0865x over previous
//
#include <hip/hip_runtime.h>
#include <hip/hip_bf16.h>

#define SCALE_F 0.125f

typedef __attribute__((ext_vector_type(8))) short short8;
typedef __attribute__((ext_vector_type(4))) float f32x4;

__device__ __forceinline__ unsigned short f2b(float f){
  unsigned int x = __float_as_uint(f);
  return (unsigned short)((x + 0x7fffu + ((x >> 16) & 1u)) >> 16);
}
__device__ __forceinline__ float b2f(unsigned short h){
  return __uint_as_float((unsigned int)h << 16);
}

// Transpose-cast W [512k,512n] f32 -> WT [n][k] bf16 (z picks which W).
__global__ __launch_bounds__(256)
void wcast_t(const float* __restrict__ W0, unsigned short* __restrict__ T0,
             const float* __restrict__ W1, unsigned short* __restrict__ T1)
{
  __shared__ unsigned short tile[64][72];
  const float* W = blockIdx.z ? W1 : W0;
  unsigned short* T = blockIdx.z ? T1 : T0;
  int k0 = blockIdx.x * 64, n0 = blockIdx.y * 64;
  #pragma unroll
  for (int j = 0; j < 16; j++) {
    int idx = threadIdx.x + j * 256;
    int r = idx >> 6, c = idx & 63;
    tile[r][c] = f2b(W[(size_t)(k0 + r) * 512 + n0 + c]);
  }
  __syncthreads();
  #pragma unroll
  for (int j = 0; j < 16; j++) {
    int idx = threadIdx.x + j * 256;
    int r = idx >> 6, c = idx & 63;
    T[(size_t)(n0 + r) * 512 + k0 + c] = tile[c][r];
  }
}

// Small-M MFMA GEMM with bf16x3 split (f32-class accuracy).
// MODE 0: plain f32 out [M,512]
// MODE 1: K=1024; k>=512 rows of A come from p0+p1 (summed in staging)
// MODE 2: Q-layout out [b,h,512,64], scaled
// MODE 3: S-layout out [b,h,32,64]
template<int MODE>
__global__ __launch_bounds__(256)
void sgemm_mfma(const float* __restrict__ A0, const float* __restrict__ A1,
                const float* __restrict__ p0, const float* __restrict__ p1,
                const float* __restrict__ W0, const float* __restrict__ W1,
                const float* __restrict__ bias0, const float* __restrict__ bias1,
                float* __restrict__ out0, float* __restrict__ out1,
                float scale, int M, int K)
{
  __shared__ unsigned short Ah[4096], Al[4096], Bh[4096], Bl[4096];
  const int z = blockIdx.z;
  const float* A    = z ? A1 : A0;
  const float* W    = z ? W1 : W0;
  const float* bias = z ? bias1 : bias0;
  float* outf       = z ? out1 : out0;

  const int m0 = blockIdx.x * 64, n0 = blockIdx.y * 64;
  const int tid = threadIdx.x;
  const int lane = tid & 63, wv = tid >> 6, lr = lane & 15, lg = lane >> 4;

  f32x4 acc[4];
  #pragma unroll
  for (int nf = 0; nf < 4; nf++) acc[nf] = (f32x4){0.f, 0.f, 0.f, 0.f};

  for (int k0 = 0; k0 < K; k0 += 64) {
    float4 a0[2], a1[2];
    float bw[2][8];
    const bool dual = (MODE == 1) && (k0 >= 512);
    const int kk = dual ? (k0 - 512) : k0;
    #pragma unroll
    for (int j = 0; j < 2; j++) {
      int idx = tid + j * 256;
      int row = idx >> 3, c8 = idx & 7;
      size_t base = (size_t)(m0 + row) * 512 + kk + c8 * 8;
      if (dual) {
        float4 x0 = *(const float4*)&p0[base];
        float4 x1 = *(const float4*)&p0[base + 4];
        float4 y0 = *(const float4*)&p1[base];
        float4 y1 = *(const float4*)&p1[base + 4];
        a0[j] = (float4){x0.x + y0.x, x0.y + y0.y, x0.z + y0.z, x0.w + y0.w};
        a1[j] = (float4){x1.x + y1.x, x1.y + y1.y, x1.z + y1.z, x1.w + y1.w};
      } else {
        a0[j] = *(const float4*)&A[base];
        a1[j] = *(const float4*)&A[base + 4];
      }
    }
    #pragma unroll
    for (int j = 0; j < 2; j++) {
      int idx = tid + j * 256;
      int nl = idx >> 3, kseg = idx & 7;
      #pragma unroll
      for (int e = 0; e < 8; e++)
        bw[j][e] = W[(size_t)(k0 + kseg * 8 + e) * 512 + n0 + nl];
    }
    __syncthreads();
    #pragma unroll
    for (int j = 0; j < 2; j++) {
      int idx = tid + j * 256;
      int row = idx >> 3, c8 = idx & 7;
      int off = row * 64 + ((c8 * 8) ^ ((row & 7) << 3));
      float v[8] = {a0[j].x, a0[j].y, a0[j].z, a0[j].w,
                    a1[j].x, a1[j].y, a1[j].z, a1[j].w};
      short8 h, l;
      #pragma unroll
      for (int e = 0; e < 8; e++) {
        unsigned short hh = f2b(v[e]);
        h[e] = (short)hh;
        l[e] = (short)f2b(v[e] - b2f(hh));
      }
      *(short8*)&Ah[off] = h;
      *(short8*)&Al[off] = l;
    }
    #pragma unroll
    for (int j = 0; j < 2; j++) {
      int idx = tid + j * 256;
      int nl = idx >> 3, kseg = idx & 7;
      int off = nl * 64 + ((kseg * 8) ^ ((nl & 7) << 3));
      short8 h, l;
      #pragma unroll
      for (int e = 0; e < 8; e++) {
        unsigned short hh = f2b(bw[j][e]);
        h[e] = (short)hh;
        l[e] = (short)f2b(bw[j][e] - b2f(hh));
      }
      *(short8*)&Bh[off] = h;
      *(short8*)&Bl[off] = l;
    }
    __syncthreads();
    #pragma unroll
    for (int ks = 0; ks < 2; ks++) {
      int rowa = wv * 16 + lr;
      int aoff = rowa * 64 + ((ks * 32 + lg * 8) ^ ((rowa & 7) << 3));
      short8 ah = *(const short8*)&Ah[aoff];
      short8 al = *(const short8*)&Al[aoff];
      #pragma unroll
      for (int nf = 0; nf < 4; nf++) {
        int rowb = nf * 16 + lr;
        int boff = rowb * 64 + ((ks * 32 + lg * 8) ^ ((rowb & 7) << 3));
        short8 bh = *(const short8*)&Bh[boff];
        short8 bl = *(const short8*)&Bl[boff];
        acc[nf] = __builtin_amdgcn_mfma_f32_16x16x32_bf16(ah, bh, acc[nf], 0, 0, 0);
        acc[nf] = __builtin_amdgcn_mfma_f32_16x16x32_bf16(ah, bl, acc[nf], 0, 0, 0);
        acc[nf] = __builtin_amdgcn_mfma_f32_16x16x32_bf16(al, bh, acc[nf], 0, 0, 0);
      }
    }
  }

  #pragma unroll
  for (int nf = 0; nf < 4; nf++) {
    int n = n0 + nf * 16 + lr;
    float bv = bias[n];
    #pragma unroll
    for (int i = 0; i < 4; i++) {
      int m = m0 + wv * 16 + lg * 4 + i;
      float v = (acc[nf][i] + bv) * scale;
      if (MODE == 0 || MODE == 1) {
        outf[(size_t)m * 512 + n] = v;
      } else if (MODE == 2) {
        int bb = m >> 9, qq = m & 511, hh = n >> 6, d = n & 63;
        outf[((((size_t)bb * 8 + hh) * 512 + qq) << 6) + d] = v;
      } else {
        int bb = m >> 5, nn = m & 31, hh = n >> 6, d = n & 63;
        outf[((((size_t)bb * 8 + hh) * 32 + nn) << 6) + d] = v;
      }
    }
  }
}

// MFMA projection GEMM, tile 128x128, BK=64, 4 waves x 64x64.
// VT=0: out bf16 [b,h,n,t(256),d(64)]  (K path, row-major in d)
// VT=1: out bf16 [b,h,n,d(64),t(256)]  (V path, TRANSPOSED: rows of t per d)
template<int VT>
__global__ __launch_bounds__(256)
void proj_gemm(const float* __restrict__ A,          // [32768,512] f32
               const unsigned short* __restrict__ BT,// [512n][512k] bf16
               const float* __restrict__ bias,       // [512]
               __hip_bfloat16* __restrict__ outW)
{
  __shared__ unsigned short As[128 * 64];
  __shared__ unsigned short Bs[128 * 64];
  const int m0 = blockIdx.x * 128, n0 = blockIdx.y * 128;
  const int tid = threadIdx.x;
  const int lane = tid & 63, wv = tid >> 6, lr = lane & 15, lg = lane >> 4;
  const int wr = wv >> 1, wc = wv & 1;

  f32x4 acc[4][4];
  #pragma unroll
  for (int mi = 0; mi < 4; mi++)
    #pragma unroll
    for (int nj = 0; nj < 4; nj++) acc[mi][nj] = (f32x4){0.f, 0.f, 0.f, 0.f};

  for (int k0 = 0; k0 < 512; k0 += 64) {
    float4 a0[4], a1[4]; uint4 bq[4];
    #pragma unroll
    for (int j = 0; j < 4; j++) {
      int idx = tid + j * 256;
      int row = idx >> 3, c8 = idx & 7;
      const float* ap = A + (size_t)(m0 + row) * 512 + k0 + c8 * 8;
      a0[j] = *(const float4*)ap;
      a1[j] = *(const float4*)(ap + 4);
      bq[j] = *(const uint4*)(BT + (size_t)(n0 + row) * 512 + k0 + c8 * 8);
    }
    __syncthreads();
    #pragma unroll
    for (int j = 0; j < 4; j++) {
      int idx = tid + j * 256;
      int row = idx >> 3, c8 = idx & 7;
      int off = row * 64 + ((c8 * 8) ^ ((row & 7) << 3));
      short8 pk;
      pk[0] = (short)f2b(a0[j].x); pk[1] = (short)f2b(a0[j].y);
      pk[2] = (short)f2b(a0[j].z); pk[3] = (short)f2b(a0[j].w);
      pk[4] = (short)f2b(a1[j].x); pk[5] = (short)f2b(a1[j].y);
      pk[6] = (short)f2b(a1[j].z); pk[7] = (short)f2b(a1[j].w);
      *(short8*)&As[off] = pk;
      *(uint4*)&Bs[off] = bq[j];
    }
    __syncthreads();
    #pragma unroll
    for (int ks = 0; ks < 2; ks++) {
      short8 af[4], bfp[4];
      #pragma unroll
      for (int mi = 0; mi < 4; mi++) {
        int row = wr * 64 + mi * 16 + lr;
        af[mi] = *(const short8*)&As[row * 64 + ((ks * 32 + lg * 8) ^ ((row & 7) << 3))];
      }
      #pragma unroll
      for (int nj = 0; nj < 4; nj++) {
        int row = wc * 64 + nj * 16 + lr;
        bfp[nj] = *(const short8*)&Bs[row * 64 + ((ks * 32 + lg * 8) ^ ((row & 7) << 3))];
      }
      #pragma unroll
      for (int mi = 0; mi < 4; mi++)
        #pragma unroll
        for (int nj = 0; nj < 4; nj++)
          acc[mi][nj] = __builtin_amdgcn_mfma_f32_16x16x32_bf16(af[mi], bfp[nj], acc[mi][nj], 0, 0, 0);
    }
  }

  #pragma unroll
  for (int nj = 0; nj < 4; nj++) {
    int n = n0 + wc * 64 + nj * 16 + lr;
    float bv = bias[n];
    int hh = n >> 6, d = n & 63;
    #pragma unroll
    for (int mi = 0; mi < 4; mi++) {
      if (VT == 0) {
        #pragma unroll
        for (int i = 0; i < 4; i++) {
          int m = m0 + wr * 64 + mi * 16 + lg * 4 + i;
          int bb = m >> 13, r = m & 8191, nn = r >> 8, tt = r & 255;
          outW[(((((size_t)bb * 8 + hh) * 32 + nn) * 256 + tt) << 6) + d] =
              __float2bfloat16(acc[mi][nj][i] + bv);
        }
      } else {
        int m = m0 + wr * 64 + mi * 16 + lg * 4;   // 4 consecutive t
        int bb = m >> 13, r = m & 8191, nn = r >> 8, t0 = r & 255;
        uint2 pk;
        pk.x = (unsigned)f2b(acc[mi][nj][0] + bv) | ((unsigned)f2b(acc[mi][nj][1] + bv) << 16);
        pk.y = (unsigned)f2b(acc[mi][nj][2] + bv) | ((unsigned)f2b(acc[mi][nj][3] + bv) << 16);
        *(uint2*)((unsigned short*)outW +
                  (((((size_t)bb * 8 + hh) * 32 + nn) * 64 + d) << 8) + t0) = pk;
      }
    }
  }
}

// Sentence-level attention: scores over nb=32, softmax, ctx_s; also emits attn_s.
__global__ __launch_bounds__(256)
void sent_attn(const float* __restrict__ qs,   // [b,h,512,64]  (pre-scaled)
               const float* __restrict__ ks,   // [b,h,32,64]
               const float* __restrict__ vs,   // [b,h,32,64]
               float* __restrict__ attn_s,     // [b,h,512,32]
               float* __restrict__ ctx_s)      // [b,512,512]
{
  __shared__ float qsS[32][68];
  __shared__ float ksS[32][68];
  __shared__ float vsS[32][68];
  __shared__ float sS[32][36];
  const int bh = blockIdx.y, b = bh >> 3, h = bh & 7;
  const int q0 = blockIdx.x * 32;
  const int tid = threadIdx.x;

  #pragma unroll
  for (int i = 0; i < 2; i++) {
    int idx = tid + i * 256;
    int r = idx >> 4, c = (idx & 15) * 4;
    *(float4*)&qsS[r][c] = *(const float4*)&qs[((size_t)bh * 512 + q0 + r) * 64 + c];
    *(float4*)&ksS[r][c] = *(const float4*)&ks[((size_t)bh * 32 + r) * 64 + c];
    *(float4*)&vsS[r][c] = *(const float4*)&vs[((size_t)bh * 32 + r) * 64 + c];
  }
  __syncthreads();

  #pragma unroll
  for (int it = 0; it < 4; it++) {
    int pair = tid + it * 256;
    int qq = pair >> 5, nn = pair & 31;
    float s = 0.f;
    #pragma unroll
    for (int k = 0; k < 64; k++) s += qsS[qq][k] * ksS[nn][k];
    sS[qq][nn] = s;
  }
  __syncthreads();

  if (tid < 32) {
    int qq = tid;
    float m = -1e30f;
    #pragma unroll
    for (int n = 0; n < 32; n++) m = fmaxf(m, sS[qq][n]);
    float p[32];
    float sum = 0.f;
    #pragma unroll
    for (int n = 0; n < 32; n++) { p[n] = __expf(sS[qq][n] - m); sum += p[n]; }
    float inv = 1.f / sum;
    #pragma unroll
    for (int n = 0; n < 32; n++) {
      float pv = p[n] * inv;
      sS[qq][n] = pv;
      attn_s[((size_t)bh * 512 + q0 + qq) * 32 + n] = pv;
    }
  }
  __syncthreads();

  #pragma unroll
  for (int it = 0; it < 8; it++) {
    int idx = tid + it * 256;
    int qq = idx >> 6, d = idx & 63;
    float c = 0.f;
    #pragma unroll
    for (int n = 0; n < 32; n++) c += sS[qq][n] * vsS[n][d];
    ctx_s[((size_t)b * 512 + q0 + qq) * 512 + h * 64 + d] = c;
  }
}

// Token-level attention v3: v1 LDS-staged structure + cheap V staging from
// transposed vwT (b128 rows, XOR-swizzled) + T14 early-issue global loads.
// 512 blocks 1D XCD-grouped (bid&7 = XCD, 16 blocks/bh on one XCD).
// 4 waves x 16 q-rows; K buf [256][72] and Vt buf [64][264] share kvbuf.
__global__ __launch_bounds__(256, 2)
void tok_attn_v3(const float* __restrict__ qw,            // [b,h,512,64] f32 pre-scaled
                 const __hip_bfloat16* __restrict__ kw,   // [b,h,32,256,64]
                 const __hip_bfloat16* __restrict__ vwT,  // [b,h,32,64,256] TRANSPOSED
                 const float* __restrict__ attn_s,        // [b,h,512,32]
                 float* __restrict__ part0,
                 float* __restrict__ part1)
{
  __shared__ unsigned short kvbuf[18432];    // K [256][72]  OR  Vt [64][264]
  __shared__ unsigned short pbuf[64 * 264];  // P [64 q-rows][256 t + 8 pad]
  const int bid = blockIdx.x;
  const int xcd = bid & 7, slot = bid >> 3;
  const int bh = xcd * 4 + (slot >> 4);
  const int rest = slot & 15;
  const int qt = rest >> 1, z = rest & 1;
  const int b = bh >> 3, h = bh & 7;
  const int tid = threadIdx.x;
  const int wv = tid >> 6, lane = tid & 63, lg = lane >> 4, lr = lane & 15;
  const int qbase = qt * 64 + wv * 16;
  const int n0 = z * 16;
  // V staging mapping: row d = wv*16 + (lane>>2), quarter tq = lane&3
  const int vd = wv * 16 + (lane >> 2), tq = lane & 3;

  short8 qfrag[2];
  {
    const float* qrow = qw + ((size_t)bh * 512 + qbase + lr) * 64;
    #pragma unroll
    for (int ks = 0; ks < 2; ks++) {
      float4 u0 = *(const float4*)&qrow[ks * 32 + lg * 8];
      float4 u1 = *(const float4*)&qrow[ks * 32 + lg * 8 + 4];
      short8 t;
      t[0] = f2b(u0.x); t[1] = f2b(u0.y); t[2] = f2b(u0.z); t[3] = f2b(u0.w);
      t[4] = f2b(u1.x); t[5] = f2b(u1.y); t[6] = f2b(u1.z); t[7] = f2b(u1.w);
      qfrag[ks] = t;
    }
  }
  float asv[16];
  {
    const float* ap = attn_s + ((size_t)bh * 512 + qbase + lr) * 32 + n0;
    #pragma unroll
    for (int i = 0; i < 4; i++) {
      float4 u = *(const float4*)&ap[i * 4];
      asv[i * 4 + 0] = u.x; asv[i * 4 + 1] = u.y;
      asv[i * 4 + 2] = u.z; asv[i * 4 + 3] = u.w;
    }
  }

  f32x4 acc[4];
  #pragma unroll
  for (int dt = 0; dt < 4; dt++) acc[dt] = (f32x4){0.f, 0.f, 0.f, 0.f};

  const unsigned short* kwb = (const unsigned short*)kw + (size_t)bh * 32 * 256 * 64;
  const unsigned short* vtb = (const unsigned short*)vwT + (size_t)bh * 32 * 64 * 256;
  const unsigned int pbase = (wv * 16 + lr) * 264;

  // prologue: K[n0] -> regs
  uint4 kreg[8];
  {
    const unsigned short* ksrc = kwb + ((size_t)n0 * 256 + tid) * 64;
    #pragma unroll
    for (int j = 0; j < 8; j++) kreg[j] = *(const uint4*)(ksrc + j * 8);
  }

  for (int ni = 0; ni < 16; ni++) {
    const int n = n0 + ni;
    __syncthreads();   // prior PV done reading kvbuf
    // write K tile (regs loaded during prior PV / prologue)
    #pragma unroll
    for (int j = 0; j < 8; j++) *(uint4*)&kvbuf[tid * 72 + j * 8] = kreg[j];
    // issue V[n] loads (land after QK, hidden under it)
    uint4 vreg[8];
    {
      const unsigned short* vsrc = vtb + ((size_t)n * 64 + vd) * 256 + tq * 64;
      #pragma unroll
      for (int j = 0; j < 8; j++) vreg[j] = *(const uint4*)(vsrc + j * 8);
    }
    __syncthreads();

    // QK: Sᵀ[t][q] via mfma(K, Q)
    f32x4 sfr[16];
    #pragma unroll
    for (int tt = 0; tt < 16; tt++) sfr[tt] = (f32x4){0.f, 0.f, 0.f, 0.f};
    #pragma unroll
    for (int tt = 0; tt < 16; tt++) {
      #pragma unroll
      for (int ks = 0; ks < 2; ks++) {
        short8 kf = *(const short8*)&kvbuf[(16 * tt + lr) * 72 + ks * 32 + lg * 8];
        sfr[tt] = __builtin_amdgcn_mfma_f32_16x16x32_bf16(kf, qfrag[ks], sfr[tt], 0, 0, 0);
      }
    }
    // softmax (shift-free) + sentence weighting for q = qbase+lr
    float lsum = 0.f;
    #pragma unroll
    for (int tt = 0; tt < 16; tt++) {
      #pragma unroll
      for (int i = 0; i < 4; i++) {
        float e = __expf(sfr[tt][i]);
        sfr[tt][i] = e;
        lsum += e;
      }
    }
    lsum += __shfl_xor(lsum, 16);
    lsum += __shfl_xor(lsum, 32);
    const float coef = asv[ni] / lsum;
    #pragma unroll
    for (int tt = 0; tt < 16; tt++) {
      uint2 pk;
      pk.x = (unsigned)f2b(sfr[tt][0] * coef) | ((unsigned)f2b(sfr[tt][1] * coef) << 16);
      pk.y = (unsigned)f2b(sfr[tt][2] * coef) | ((unsigned)f2b(sfr[tt][3] * coef) << 16);
      *(uint2*)&pbuf[pbase + tt * 16 + lg * 4] = pk;
    }
    __syncthreads();   // all QK reads of kvbuf done

    // write Vt tile from regs (b128, j^tq swizzle on 16B sub-blocks)
    #pragma unroll
    for (int j = 0; j < 8; j++)
      *(uint4*)&kvbuf[vd * 264 + tq * 64 + ((j ^ tq) * 8)] = vreg[j];
    // issue K[ni+1] loads (hidden under PV)
    {
      const int nn = (ni < 15) ? (n + 1) : n;
      const unsigned short* ksrc = kwb + ((size_t)nn * 256 + tid) * 64;
      #pragma unroll
      for (int j = 0; j < 8; j++) kreg[j] = *(const uint4*)(ksrc + j * 8);
    }
    __syncthreads();

    // PV: acc[q][d] += P[q][t] * V[t][d]
    #pragma unroll
    for (int ks = 0; ks < 8; ks++) {
      short8 pa = *(const short8*)&pbuf[pbase + ks * 32 + lg * 8];
      const int tqe = ks >> 1, joff = (ks & 1) * 4 + lg;
      #pragma unroll
      for (int dt = 0; dt < 4; dt++) {
        short8 vb = *(const short8*)&kvbuf[(16 * dt + lr) * 264 + tqe * 64 + ((joff ^ tqe) * 8)];
        acc[dt] = __builtin_amdgcn_mfma_f32_16x16x32_bf16(pa, vb, acc[dt], 0, 0, 0);
      }
    }
  }

  float* pout = z ? part1 : part0;
  #pragma unroll
  for (int dt = 0; dt < 4; dt++) {
    #pragma unroll
    for (int i = 0; i < 4; i++) {
      int qg = qt * 64 + wv * 16 + lg * 4 + i;
      pout[((size_t)b * 512 + qg) * 512 + h * 64 + dt * 16 + lr] = acc[dt][i];
    }
  }
}

extern "C" void kernel_launch(void* const* d_in, const int* in_sizes, int n_in,
                              void* d_out, int out_size, void* d_ws, size_t ws_size,
                              hipStream_t stream)
{
  (void)in_sizes; (void)n_in; (void)out_size; (void)ws_size;
  const float* q    = (const float*)d_in[0];
  const float* k_w  = (const float*)d_in[1];
  const float* v_w  = (const float*)d_in[2];
  const float* k_s  = (const float*)d_in[3];
  const float* v_s  = (const float*)d_in[4];
  const float* W_qs = (const float*)d_in[5];  const float* b_qs = (const float*)d_in[6];
  const float* W_ks = (const float*)d_in[7];  const float* b_ks = (const float*)d_in[8];
  const float* W_vs = (const float*)d_in[9];  const float* b_vs = (const float*)d_in[10];
  const float* W_qw = (const float*)d_in[11]; const float* b_qw = (const float*)d_in[12];
  const float* W_kw = (const float*)d_in[13]; const float* b_kw = (const float*)d_in[14];
  const float* W_vw = (const float*)d_in[15]; const float* b_vw = (const float*)d_in[16];
  const float* W_fc1= (const float*)d_in[17]; const float* b_fc1= (const float*)d_in[18];
  const float* W_fc = (const float*)d_in[19]; const float* b_fc = (const float*)d_in[20];
  float* out = (float*)d_out;

  char* ws = (char*)d_ws;
  const size_t MB = 1ull << 20;
  const size_t KB = 1ull << 10;
  float* qs_ws    = (float*)(ws + 0 * MB);       // [b,h,512,64] 4 MB (dead after sent_attn)
  float* qw_ws    = (float*)(ws + 4 * MB);       // [b,h,512,64] 4 MB
  float* ks_ws    = (float*)(ws + 8 * MB);       // [b,h,32,64] 256 KB
  unsigned short* WkT = (unsigned short*)(ws + 8 * MB + 512 * KB);  // 512 KB
  float* vs_ws    = (float*)(ws + 9 * MB);       // [b,h,32,64] 256 KB
  unsigned short* WvT = (unsigned short*)(ws + 9 * MB + 512 * KB);  // 512 KB
  float* attns_ws = (float*)(ws + 10 * MB);      // [b,h,512,32] 2 MB
  float* ctxs_ws  = (float*)(ws + 12 * MB);      // [b,512,512] 4 MB (dead after fc1 gemm)
  float* ctxsf_ws = (float*)(ws + 16 * MB);      // [b,512,512] 4 MB
  __hip_bfloat16* kw_ws  = (__hip_bfloat16*)(ws + 24 * MB);  // [b,h,32,256,64] 32 MB
  __hip_bfloat16* vwT_ws = (__hip_bfloat16*)(ws + 56 * MB);  // [b,h,32,64,256] 32 MB
  float* part0 = (float*)(ws + 0 * MB);          // over qs_ws   (4 MB)
  float* part1 = (float*)(ws + 12 * MB);         // over ctxs_ws (4 MB)

  dim3 blk(256);
  // weight transpose-casts for the MFMA projections
  wcast_t<<<dim3(8, 8, 2), blk, 0, stream>>>(W_kw, WkT, W_vw, WvT);
  // small projections (MFMA, bf16x3 split): qs+qw fused, ks+vs fused
  sgemm_mfma<2><<<dim3(32, 8, 2), blk, 0, stream>>>(
      q, q, nullptr, nullptr, W_qs, W_qw, b_qs, b_qw, qs_ws, qw_ws, SCALE_F, 2048, 512);
  sgemm_mfma<3><<<dim3(2, 8, 2), blk, 0, stream>>>(
      k_s, v_s, nullptr, nullptr, W_ks, W_vs, b_ks, b_vs, ks_ws, vs_ws, 1.f, 128, 512);
  // big projections (MFMA): K row-major, V transposed for cheap tok-attn staging
  proj_gemm<0><<<dim3(256, 4), blk, 0, stream>>>(k_w, WkT, b_kw, kw_ws);
  proj_gemm<1><<<dim3(256, 4), blk, 0, stream>>>(v_w, WvT, b_vw, vwT_ws);
  // sentence attention (+ attn_s for token level)
  sent_attn<<<dim3(16, 32), blk, 0, stream>>>(qs_ws, ks_ws, vs_ws, attns_ws, ctxs_ws);
  // ctx_s @ W_fc1
  sgemm_mfma<0><<<dim3(32, 8, 1), blk, 0, stream>>>(
      ctxs_ws, ctxs_ws, nullptr, nullptr, W_fc1, W_fc1, b_fc1, b_fc1,
      ctxsf_ws, ctxsf_ws, 1.f, 2048, 512);
  // token attention v3 (staged, prefetched, XCD-grouped) -> partials
  tok_attn_v3<<<dim3(512), blk, 0, stream>>>(qw_ws, kw_ws, vwT_ws, attns_ws, part0, part1);
  // final combine: concat([ctx_s_fc1, part0+part1]) @ W_fc + b_fc
  sgemm_mfma<1><<<dim3(32, 8, 1), blk, 0, stream>>>(
      ctxsf_ws, ctxsf_ws, part0, part1, W_fc, W_fc, b_fc, b_fc,
      out, out, 1.f, 2048, 1024);
}

// Round 8
// 347.036 us; speedup vs baseline: 1.4416x; 1.3268x over previous
//
#include <hip/hip_runtime.h>
#include <hip/hip_bf16.h>

#define SCALE_F 0.125f

typedef __attribute__((ext_vector_type(8))) short short8;
typedef __attribute__((ext_vector_type(4))) float f32x4;

__device__ __forceinline__ unsigned short f2b(float f){
  unsigned int x = __float_as_uint(f);
  return (unsigned short)((x + 0x7fffu + ((x >> 16) & 1u)) >> 16);
}
__device__ __forceinline__ float b2f(unsigned short h){
  return __uint_as_float((unsigned int)h << 16);
}

// Transpose-cast W [512k,512n] f32 -> WT [n][k] bf16 (z picks which W).
__global__ __launch_bounds__(256)
void wcast_t(const float* __restrict__ W0, unsigned short* __restrict__ T0,
             const float* __restrict__ W1, unsigned short* __restrict__ T1)
{
  __shared__ unsigned short tile[64][72];
  const float* W = blockIdx.z ? W1 : W0;
  unsigned short* T = blockIdx.z ? T1 : T0;
  int k0 = blockIdx.x * 64, n0 = blockIdx.y * 64;
  #pragma unroll
  for (int j = 0; j < 16; j++) {
    int idx = threadIdx.x + j * 256;
    int r = idx >> 6, c = idx & 63;
    tile[r][c] = f2b(W[(size_t)(k0 + r) * 512 + n0 + c]);
  }
  __syncthreads();
  #pragma unroll
  for (int j = 0; j < 16; j++) {
    int idx = threadIdx.x + j * 256;
    int r = idx >> 6, c = idx & 63;
    T[(size_t)(n0 + r) * 512 + k0 + c] = tile[c][r];
  }
}

// Small-M MFMA GEMM with bf16x3 split (f32-class accuracy).
// MODE 0: plain f32 out [M,512]
// MODE 1: K=1024; k>=512 rows of A come from p0+p1 (summed in staging)
// MODE 2: Q-layout out [b,h,512,64], scaled
// MODE 3: S-layout out [b,h,32,64]
template<int MODE>
__global__ __launch_bounds__(256)
void sgemm_mfma(const float* __restrict__ A0, const float* __restrict__ A1,
                const float* __restrict__ p0, const float* __restrict__ p1,
                const float* __restrict__ W0, const float* __restrict__ W1,
                const float* __restrict__ bias0, const float* __restrict__ bias1,
                float* __restrict__ out0, float* __restrict__ out1,
                float scale, int M, int K)
{
  __shared__ unsigned short Ah[4096], Al[4096], Bh[4096], Bl[4096];
  const int z = blockIdx.z;
  const float* A    = z ? A1 : A0;
  const float* W    = z ? W1 : W0;
  const float* bias = z ? bias1 : bias0;
  float* outf       = z ? out1 : out0;

  const int m0 = blockIdx.x * 64, n0 = blockIdx.y * 64;
  const int tid = threadIdx.x;
  const int lane = tid & 63, wv = tid >> 6, lr = lane & 15, lg = lane >> 4;

  f32x4 acc[4];
  #pragma unroll
  for (int nf = 0; nf < 4; nf++) acc[nf] = (f32x4){0.f, 0.f, 0.f, 0.f};

  for (int k0 = 0; k0 < K; k0 += 64) {
    float4 a0[2], a1[2];
    float bw[2][8];
    const bool dual = (MODE == 1) && (k0 >= 512);
    const int kk = dual ? (k0 - 512) : k0;
    #pragma unroll
    for (int j = 0; j < 2; j++) {
      int idx = tid + j * 256;
      int row = idx >> 3, c8 = idx & 7;
      size_t base = (size_t)(m0 + row) * 512 + kk + c8 * 8;
      if (dual) {
        float4 x0 = *(const float4*)&p0[base];
        float4 x1 = *(const float4*)&p0[base + 4];
        float4 y0 = *(const float4*)&p1[base];
        float4 y1 = *(const float4*)&p1[base + 4];
        a0[j] = (float4){x0.x + y0.x, x0.y + y0.y, x0.z + y0.z, x0.w + y0.w};
        a1[j] = (float4){x1.x + y1.x, x1.y + y1.y, x1.z + y1.z, x1.w + y1.w};
      } else {
        a0[j] = *(const float4*)&A[base];
        a1[j] = *(const float4*)&A[base + 4];
      }
    }
    #pragma unroll
    for (int j = 0; j < 2; j++) {
      int idx = tid + j * 256;
      int nl = idx >> 3, kseg = idx & 7;
      #pragma unroll
      for (int e = 0; e < 8; e++)
        bw[j][e] = W[(size_t)(k0 + kseg * 8 + e) * 512 + n0 + nl];
    }
    __syncthreads();
    #pragma unroll
    for (int j = 0; j < 2; j++) {
      int idx = tid + j * 256;
      int row = idx >> 3, c8 = idx & 7;
      int off = row * 64 + ((c8 * 8) ^ ((row & 7) << 3));
      float v[8] = {a0[j].x, a0[j].y, a0[j].z, a0[j].w,
                    a1[j].x, a1[j].y, a1[j].z, a1[j].w};
      short8 h, l;
      #pragma unroll
      for (int e = 0; e < 8; e++) {
        unsigned short hh = f2b(v[e]);
        h[e] = (short)hh;
        l[e] = (short)f2b(v[e] - b2f(hh));
      }
      *(short8*)&Ah[off] = h;
      *(short8*)&Al[off] = l;
    }
    #pragma unroll
    for (int j = 0; j < 2; j++) {
      int idx = tid + j * 256;
      int nl = idx >> 3, kseg = idx & 7;
      int off = nl * 64 + ((kseg * 8) ^ ((nl & 7) << 3));
      short8 h, l;
      #pragma unroll
      for (int e = 0; e < 8; e++) {
        unsigned short hh = f2b(bw[j][e]);
        h[e] = (short)hh;
        l[e] = (short)f2b(bw[j][e] - b2f(hh));
      }
      *(short8*)&Bh[off] = h;
      *(short8*)&Bl[off] = l;
    }
    __syncthreads();
    #pragma unroll
    for (int ks = 0; ks < 2; ks++) {
      int rowa = wv * 16 + lr;
      int aoff = rowa * 64 + ((ks * 32 + lg * 8) ^ ((rowa & 7) << 3));
      short8 ah = *(const short8*)&Ah[aoff];
      short8 al = *(const short8*)&Al[aoff];
      #pragma unroll
      for (int nf = 0; nf < 4; nf++) {
        int rowb = nf * 16 + lr;
        int boff = rowb * 64 + ((ks * 32 + lg * 8) ^ ((rowb & 7) << 3));
        short8 bh = *(const short8*)&Bh[boff];
        short8 bl = *(const short8*)&Bl[boff];
        acc[nf] = __builtin_amdgcn_mfma_f32_16x16x32_bf16(ah, bh, acc[nf], 0, 0, 0);
        acc[nf] = __builtin_amdgcn_mfma_f32_16x16x32_bf16(ah, bl, acc[nf], 0, 0, 0);
        acc[nf] = __builtin_amdgcn_mfma_f32_16x16x32_bf16(al, bh, acc[nf], 0, 0, 0);
      }
    }
  }

  #pragma unroll
  for (int nf = 0; nf < 4; nf++) {
    int n = n0 + nf * 16 + lr;
    float bv = bias[n];
    #pragma unroll
    for (int i = 0; i < 4; i++) {
      int m = m0 + wv * 16 + lg * 4 + i;
      float v = (acc[nf][i] + bv) * scale;
      if (MODE == 0 || MODE == 1) {
        outf[(size_t)m * 512 + n] = v;
      } else if (MODE == 2) {
        int bb = m >> 9, qq = m & 511, hh = n >> 6, d = n & 63;
        outf[((((size_t)bb * 8 + hh) * 512 + qq) << 6) + d] = v;
      } else {
        int bb = m >> 5, nn = m & 31, hh = n >> 6, d = n & 63;
        outf[((((size_t)bb * 8 + hh) * 32 + nn) << 6) + d] = v;
      }
    }
  }
}

// MFMA projection GEMM, tile 128x128, BK=64, 4 waves x 64x64.
// VT=0: out bf16 [b,h,n,t(256),d(64)]  (K path, row-major in d)
// VT=1: out bf16 [b,h,n,d(64),t(256)]  (V path, TRANSPOSED: rows of t per d)
template<int VT>
__global__ __launch_bounds__(256)
void proj_gemm(const float* __restrict__ A,          // [32768,512] f32
               const unsigned short* __restrict__ BT,// [512n][512k] bf16
               const float* __restrict__ bias,       // [512]
               __hip_bfloat16* __restrict__ outW)
{
  __shared__ unsigned short As[128 * 64];
  __shared__ unsigned short Bs[128 * 64];
  const int m0 = blockIdx.x * 128, n0 = blockIdx.y * 128;
  const int tid = threadIdx.x;
  const int lane = tid & 63, wv = tid >> 6, lr = lane & 15, lg = lane >> 4;
  const int wr = wv >> 1, wc = wv & 1;

  f32x4 acc[4][4];
  #pragma unroll
  for (int mi = 0; mi < 4; mi++)
    #pragma unroll
    for (int nj = 0; nj < 4; nj++) acc[mi][nj] = (f32x4){0.f, 0.f, 0.f, 0.f};

  for (int k0 = 0; k0 < 512; k0 += 64) {
    float4 a0[4], a1[4]; uint4 bq[4];
    #pragma unroll
    for (int j = 0; j < 4; j++) {
      int idx = tid + j * 256;
      int row = idx >> 3, c8 = idx & 7;
      const float* ap = A + (size_t)(m0 + row) * 512 + k0 + c8 * 8;
      a0[j] = *(const float4*)ap;
      a1[j] = *(const float4*)(ap + 4);
      bq[j] = *(const uint4*)(BT + (size_t)(n0 + row) * 512 + k0 + c8 * 8);
    }
    __syncthreads();
    #pragma unroll
    for (int j = 0; j < 4; j++) {
      int idx = tid + j * 256;
      int row = idx >> 3, c8 = idx & 7;
      int off = row * 64 + ((c8 * 8) ^ ((row & 7) << 3));
      short8 pk;
      pk[0] = (short)f2b(a0[j].x); pk[1] = (short)f2b(a0[j].y);
      pk[2] = (short)f2b(a0[j].z); pk[3] = (short)f2b(a0[j].w);
      pk[4] = (short)f2b(a1[j].x); pk[5] = (short)f2b(a1[j].y);
      pk[6] = (short)f2b(a1[j].z); pk[7] = (short)f2b(a1[j].w);
      *(short8*)&As[off] = pk;
      *(uint4*)&Bs[off] = bq[j];
    }
    __syncthreads();
    #pragma unroll
    for (int ks = 0; ks < 2; ks++) {
      short8 af[4], bfp[4];
      #pragma unroll
      for (int mi = 0; mi < 4; mi++) {
        int row = wr * 64 + mi * 16 + lr;
        af[mi] = *(const short8*)&As[row * 64 + ((ks * 32 + lg * 8) ^ ((row & 7) << 3))];
      }
      #pragma unroll
      for (int nj = 0; nj < 4; nj++) {
        int row = wc * 64 + nj * 16 + lr;
        bfp[nj] = *(const short8*)&Bs[row * 64 + ((ks * 32 + lg * 8) ^ ((row & 7) << 3))];
      }
      #pragma unroll
      for (int mi = 0; mi < 4; mi++)
        #pragma unroll
        for (int nj = 0; nj < 4; nj++)
          acc[mi][nj] = __builtin_amdgcn_mfma_f32_16x16x32_bf16(af[mi], bfp[nj], acc[mi][nj], 0, 0, 0);
    }
  }

  #pragma unroll
  for (int nj = 0; nj < 4; nj++) {
    int n = n0 + wc * 64 + nj * 16 + lr;
    float bv = bias[n];
    int hh = n >> 6, d = n & 63;
    #pragma unroll
    for (int mi = 0; mi < 4; mi++) {
      if (VT == 0) {
        #pragma unroll
        for (int i = 0; i < 4; i++) {
          int m = m0 + wr * 64 + mi * 16 + lg * 4 + i;
          int bb = m >> 13, r = m & 8191, nn = r >> 8, tt = r & 255;
          outW[(((((size_t)bb * 8 + hh) * 32 + nn) * 256 + tt) << 6) + d] =
              __float2bfloat16(acc[mi][nj][i] + bv);
        }
      } else {
        int m = m0 + wr * 64 + mi * 16 + lg * 4;   // 4 consecutive t
        int bb = m >> 13, r = m & 8191, nn = r >> 8, t0 = r & 255;
        uint2 pk;
        pk.x = (unsigned)f2b(acc[mi][nj][0] + bv) | ((unsigned)f2b(acc[mi][nj][1] + bv) << 16);
        pk.y = (unsigned)f2b(acc[mi][nj][2] + bv) | ((unsigned)f2b(acc[mi][nj][3] + bv) << 16);
        *(uint2*)((unsigned short*)outW +
                  (((((size_t)bb * 8 + hh) * 32 + nn) * 64 + d) << 8) + t0) = pk;
      }
    }
  }
}

// Sentence-level attention: scores over nb=32, softmax, ctx_s; also emits attn_s.
__global__ __launch_bounds__(256)
void sent_attn(const float* __restrict__ qs,   // [b,h,512,64]  (pre-scaled)
               const float* __restrict__ ks,   // [b,h,32,64]
               const float* __restrict__ vs,   // [b,h,32,64]
               float* __restrict__ attn_s,     // [b,h,512,32]
               float* __restrict__ ctx_s)      // [b,512,512]
{
  __shared__ float qsS[32][68];
  __shared__ float ksS[32][68];
  __shared__ float vsS[32][68];
  __shared__ float sS[32][36];
  const int bh = blockIdx.y, b = bh >> 3, h = bh & 7;
  const int q0 = blockIdx.x * 32;
  const int tid = threadIdx.x;

  #pragma unroll
  for (int i = 0; i < 2; i++) {
    int idx = tid + i * 256;
    int r = idx >> 4, c = (idx & 15) * 4;
    *(float4*)&qsS[r][c] = *(const float4*)&qs[((size_t)bh * 512 + q0 + r) * 64 + c];
    *(float4*)&ksS[r][c] = *(const float4*)&ks[((size_t)bh * 32 + r) * 64 + c];
    *(float4*)&vsS[r][c] = *(const float4*)&vs[((size_t)bh * 32 + r) * 64 + c];
  }
  __syncthreads();

  #pragma unroll
  for (int it = 0; it < 4; it++) {
    int pair = tid + it * 256;
    int qq = pair >> 5, nn = pair & 31;
    float s = 0.f;
    #pragma unroll
    for (int k = 0; k < 64; k++) s += qsS[qq][k] * ksS[nn][k];
    sS[qq][nn] = s;
  }
  __syncthreads();

  if (tid < 32) {
    int qq = tid;
    float m = -1e30f;
    #pragma unroll
    for (int n = 0; n < 32; n++) m = fmaxf(m, sS[qq][n]);
    float p[32];
    float sum = 0.f;
    #pragma unroll
    for (int n = 0; n < 32; n++) { p[n] = __expf(sS[qq][n] - m); sum += p[n]; }
    float inv = 1.f / sum;
    #pragma unroll
    for (int n = 0; n < 32; n++) {
      float pv = p[n] * inv;
      sS[qq][n] = pv;
      attn_s[((size_t)bh * 512 + q0 + qq) * 32 + n] = pv;
    }
  }
  __syncthreads();

  #pragma unroll
  for (int it = 0; it < 8; it++) {
    int idx = tid + it * 256;
    int qq = idx >> 6, d = idx & 63;
    float c = 0.f;
    #pragma unroll
    for (int n = 0; n < 32; n++) c += sS[qq][n] * vsS[n][d];
    ctx_s[((size_t)b * 512 + q0 + qq) * 512 + h * 64 + d] = c;
  }
}

// Token-level attention v4: round-5 v1 structure (LDS-staged, 4 barriers,
// no persistent prefetch regs) + XCD-grouped 1D grid (validated: -115MB
// fetch) + cheap V staging from transposed vwT via 8x ds_write_b128 with
// j^tq sub-block swizzle (validated mapping, replaces 64x ds_write_b16).
__global__ __launch_bounds__(256, 2)
void tok_attn_v4(const float* __restrict__ qw,            // [b,h,512,64] f32 pre-scaled
                 const __hip_bfloat16* __restrict__ kw,   // [b,h,32,256,64]
                 const __hip_bfloat16* __restrict__ vwT,  // [b,h,32,64,256] TRANSPOSED
                 const float* __restrict__ attn_s,        // [b,h,512,32]
                 float* __restrict__ part0,
                 float* __restrict__ part1)
{
  __shared__ unsigned short kvbuf[18432];    // K [256][72]  OR  Vt [64][264]
  __shared__ unsigned short pbuf[64 * 264];  // P [64 q-rows][256 t + 8 pad]
  const int bid = blockIdx.x;
  const int xcd = bid & 7, slot = bid >> 3;
  const int bh = xcd * 4 + (slot >> 4);
  const int rest = slot & 15;
  const int qt = rest >> 1, z = rest & 1;
  const int b = bh >> 3, h = bh & 7;
  const int tid = threadIdx.x;
  const int wv = tid >> 6, lane = tid & 63, lg = lane >> 4, lr = lane & 15;
  const int qbase = qt * 64 + wv * 16;
  const int n0 = z * 16;
  // V staging mapping: row d = wv*16 + (lane>>2), quarter tq = lane&3
  const int vd = wv * 16 + (lane >> 2), tq = lane & 3;

  short8 qfrag[2];
  {
    const float* qrow = qw + ((size_t)bh * 512 + qbase + lr) * 64;
    #pragma unroll
    for (int ks = 0; ks < 2; ks++) {
      float4 u0 = *(const float4*)&qrow[ks * 32 + lg * 8];
      float4 u1 = *(const float4*)&qrow[ks * 32 + lg * 8 + 4];
      short8 t;
      t[0] = f2b(u0.x); t[1] = f2b(u0.y); t[2] = f2b(u0.z); t[3] = f2b(u0.w);
      t[4] = f2b(u1.x); t[5] = f2b(u1.y); t[6] = f2b(u1.z); t[7] = f2b(u1.w);
      qfrag[ks] = t;
    }
  }
  float asv[16];
  {
    const float* ap = attn_s + ((size_t)bh * 512 + qbase + lr) * 32 + n0;
    #pragma unroll
    for (int i = 0; i < 4; i++) {
      float4 u = *(const float4*)&ap[i * 4];
      asv[i * 4 + 0] = u.x; asv[i * 4 + 1] = u.y;
      asv[i * 4 + 2] = u.z; asv[i * 4 + 3] = u.w;
    }
  }

  f32x4 acc[4];
  #pragma unroll
  for (int dt = 0; dt < 4; dt++) acc[dt] = (f32x4){0.f, 0.f, 0.f, 0.f};

  const unsigned short* kwb = (const unsigned short*)kw + (size_t)bh * 32 * 256 * 64;
  const unsigned short* vtb = (const unsigned short*)vwT + (size_t)bh * 32 * 64 * 256;
  const unsigned int pbase = (wv * 16 + lr) * 264;

  for (int ni = 0; ni < 16; ni++) {
    const int n = n0 + ni;
    __syncthreads();   // prior PV done reading kvbuf
    {  // stage K: one row per thread, immediate global->reg->LDS
      const unsigned short* ksrc = kwb + ((size_t)n * 256 + tid) * 64;
      uint4 r[8];
      #pragma unroll
      for (int j = 0; j < 8; j++) r[j] = *(const uint4*)(ksrc + j * 8);
      #pragma unroll
      for (int j = 0; j < 8; j++) *(uint4*)&kvbuf[tid * 72 + j * 8] = r[j];
    }
    __syncthreads();

    // QK: Sᵀ[t][q] via mfma(K, Q)
    f32x4 sfr[16];
    #pragma unroll
    for (int tt = 0; tt < 16; tt++) sfr[tt] = (f32x4){0.f, 0.f, 0.f, 0.f};
    #pragma unroll
    for (int tt = 0; tt < 16; tt++) {
      #pragma unroll
      for (int ks = 0; ks < 2; ks++) {
        short8 kf = *(const short8*)&kvbuf[(16 * tt + lr) * 72 + ks * 32 + lg * 8];
        sfr[tt] = __builtin_amdgcn_mfma_f32_16x16x32_bf16(kf, qfrag[ks], sfr[tt], 0, 0, 0);
      }
    }
    // softmax (shift-free) + sentence weighting for q = qbase+lr
    float lsum = 0.f;
    #pragma unroll
    for (int tt = 0; tt < 16; tt++) {
      #pragma unroll
      for (int i = 0; i < 4; i++) {
        float e = __expf(sfr[tt][i]);
        sfr[tt][i] = e;
        lsum += e;
      }
    }
    lsum += __shfl_xor(lsum, 16);
    lsum += __shfl_xor(lsum, 32);
    const float coef = asv[ni] / lsum;
    #pragma unroll
    for (int tt = 0; tt < 16; tt++) {
      uint2 pk;
      pk.x = (unsigned)f2b(sfr[tt][0] * coef) | ((unsigned)f2b(sfr[tt][1] * coef) << 16);
      pk.y = (unsigned)f2b(sfr[tt][2] * coef) | ((unsigned)f2b(sfr[tt][3] * coef) << 16);
      *(uint2*)&pbuf[pbase + tt * 16 + lg * 4] = pk;
    }
    __syncthreads();   // all QK reads of kvbuf done

    {  // stage V from vwT: b128 rows, j^tq swizzle, immediate global->reg->LDS
      const unsigned short* vsrc = vtb + ((size_t)n * 64 + vd) * 256 + tq * 64;
      uint4 r[8];
      #pragma unroll
      for (int j = 0; j < 8; j++) r[j] = *(const uint4*)(vsrc + j * 8);
      #pragma unroll
      for (int j = 0; j < 8; j++)
        *(uint4*)&kvbuf[vd * 264 + tq * 64 + ((j ^ tq) * 8)] = r[j];
    }
    __syncthreads();

    // PV: acc[q][d] += P[q][t] * V[t][d]
    #pragma unroll
    for (int ks = 0; ks < 8; ks++) {
      short8 pa = *(const short8*)&pbuf[pbase + ks * 32 + lg * 8];
      const int tqe = ks >> 1, joff = (ks & 1) * 4 + lg;
      #pragma unroll
      for (int dt = 0; dt < 4; dt++) {
        short8 vb = *(const short8*)&kvbuf[(16 * dt + lr) * 264 + tqe * 64 + ((joff ^ tqe) * 8)];
        acc[dt] = __builtin_amdgcn_mfma_f32_16x16x32_bf16(pa, vb, acc[dt], 0, 0, 0);
      }
    }
  }

  float* pout = z ? part1 : part0;
  #pragma unroll
  for (int dt = 0; dt < 4; dt++) {
    #pragma unroll
    for (int i = 0; i < 4; i++) {
      int qg = qt * 64 + wv * 16 + lg * 4 + i;
      pout[((size_t)b * 512 + qg) * 512 + h * 64 + dt * 16 + lr] = acc[dt][i];
    }
  }
}

extern "C" void kernel_launch(void* const* d_in, const int* in_sizes, int n_in,
                              void* d_out, int out_size, void* d_ws, size_t ws_size,
                              hipStream_t stream)
{
  (void)in_sizes; (void)n_in; (void)out_size; (void)ws_size;
  const float* q    = (const float*)d_in[0];
  const float* k_w  = (const float*)d_in[1];
  const float* v_w  = (const float*)d_in[2];
  const float* k_s  = (const float*)d_in[3];
  const float* v_s  = (const float*)d_in[4];
  const float* W_qs = (const float*)d_in[5];  const float* b_qs = (const float*)d_in[6];
  const float* W_ks = (const float*)d_in[7];  const float* b_ks = (const float*)d_in[8];
  const float* W_vs = (const float*)d_in[9];  const float* b_vs = (const float*)d_in[10];
  const float* W_qw = (const float*)d_in[11]; const float* b_qw = (const float*)d_in[12];
  const float* W_kw = (const float*)d_in[13]; const float* b_kw = (const float*)d_in[14];
  const float* W_vw = (const float*)d_in[15]; const float* b_vw = (const float*)d_in[16];
  const float* W_fc1= (const float*)d_in[17]; const float* b_fc1= (const float*)d_in[18];
  const float* W_fc = (const float*)d_in[19]; const float* b_fc = (const float*)d_in[20];
  float* out = (float*)d_out;

  char* ws = (char*)d_ws;
  const size_t MB = 1ull << 20;
  const size_t KB = 1ull << 10;
  float* qs_ws    = (float*)(ws + 0 * MB);       // [b,h,512,64] 4 MB (dead after sent_attn)
  float* qw_ws    = (float*)(ws + 4 * MB);       // [b,h,512,64] 4 MB
  float* ks_ws    = (float*)(ws + 8 * MB);       // [b,h,32,64] 256 KB
  unsigned short* WkT = (unsigned short*)(ws + 8 * MB + 512 * KB);  // 512 KB
  float* vs_ws    = (float*)(ws + 9 * MB);       // [b,h,32,64] 256 KB
  unsigned short* WvT = (unsigned short*)(ws + 9 * MB + 512 * KB);  // 512 KB
  float* attns_ws = (float*)(ws + 10 * MB);      // [b,h,512,32] 2 MB
  float* ctxs_ws  = (float*)(ws + 12 * MB);      // [b,512,512] 4 MB (dead after fc1 gemm)
  float* ctxsf_ws = (float*)(ws + 16 * MB);      // [b,512,512] 4 MB
  __hip_bfloat16* kw_ws  = (__hip_bfloat16*)(ws + 24 * MB);  // [b,h,32,256,64] 32 MB
  __hip_bfloat16* vwT_ws = (__hip_bfloat16*)(ws + 56 * MB);  // [b,h,32,64,256] 32 MB
  float* part0 = (float*)(ws + 0 * MB);          // over qs_ws   (4 MB)
  float* part1 = (float*)(ws + 12 * MB);         // over ctxs_ws (4 MB)

  dim3 blk(256);
  // weight transpose-casts for the MFMA projections
  wcast_t<<<dim3(8, 8, 2), blk, 0, stream>>>(W_kw, WkT, W_vw, WvT);
  // small projections (MFMA, bf16x3 split): qs+qw fused, ks+vs fused
  sgemm_mfma<2><<<dim3(32, 8, 2), blk, 0, stream>>>(
      q, q, nullptr, nullptr, W_qs, W_qw, b_qs, b_qw, qs_ws, qw_ws, SCALE_F, 2048, 512);
  sgemm_mfma<3><<<dim3(2, 8, 2), blk, 0, stream>>>(
      k_s, v_s, nullptr, nullptr, W_ks, W_vs, b_ks, b_vs, ks_ws, vs_ws, 1.f, 128, 512);
  // big projections (MFMA): K row-major, V transposed for cheap tok-attn staging
  proj_gemm<0><<<dim3(256, 4), blk, 0, stream>>>(k_w, WkT, b_kw, kw_ws);
  proj_gemm<1><<<dim3(256, 4), blk, 0, stream>>>(v_w, WvT, b_vw, vwT_ws);
  // sentence attention (+ attn_s for token level)
  sent_attn<<<dim3(16, 32), blk, 0, stream>>>(qs_ws, ks_ws, vs_ws, attns_ws, ctxs_ws);
  // ctx_s @ W_fc1
  sgemm_mfma<0><<<dim3(32, 8, 1), blk, 0, stream>>>(
      ctxs_ws, ctxs_ws, nullptr, nullptr, W_fc1, W_fc1, b_fc1, b_fc1,
      ctxsf_ws, ctxsf_ws, 1.f, 2048, 512);
  // token attention v4 (staged, XCD-grouped, cheap V staging) -> partials
  tok_attn_v4<<<dim3(512), blk, 0, stream>>>(qw_ws, kw_ws, vwT_ws, attns_ws, part0, part1);
  // final combine: concat([ctx_s_fc1, part0+part1]) @ W_fc + b_fc
  sgemm_mfma<1><<<dim3(32, 8, 1), blk, 0, stream>>>(
      ctxsf_ws, ctxsf_ws, part0, part1, W_fc, W_fc, b_fc, b_fc,
      out, out, 1.f, 2048, 1024);
}

// Round 9
// 330.387 us; speedup vs baseline: 1.5142x; 1.0504x over previous
//
#include <hip/hip_runtime.h>
#include <hip/hip_bf16.h>

#define SCALE_F 0.125f

typedef __attribute__((ext_vector_type(8))) short short8;
typedef __attribute__((ext_vector_type(4))) float f32x4;

__device__ __forceinline__ unsigned short f2b(float f){
  unsigned int x = __float_as_uint(f);
  return (unsigned short)((x + 0x7fffu + ((x >> 16) & 1u)) >> 16);
}
__device__ __forceinline__ float b2f(unsigned short h){
  return __uint_as_float((unsigned int)h << 16);
}

// Transpose-cast W [512k,512n] f32 -> WT [n][k] bf16 (z picks which W).
__global__ __launch_bounds__(256)
void wcast_t(const float* __restrict__ W0, unsigned short* __restrict__ T0,
             const float* __restrict__ W1, unsigned short* __restrict__ T1)
{
  __shared__ unsigned short tile[64][72];
  const float* W = blockIdx.z ? W1 : W0;
  unsigned short* T = blockIdx.z ? T1 : T0;
  int k0 = blockIdx.x * 64, n0 = blockIdx.y * 64;
  #pragma unroll
  for (int j = 0; j < 16; j++) {
    int idx = threadIdx.x + j * 256;
    int r = idx >> 6, c = idx & 63;
    tile[r][c] = f2b(W[(size_t)(k0 + r) * 512 + n0 + c]);
  }
  __syncthreads();
  #pragma unroll
  for (int j = 0; j < 16; j++) {
    int idx = threadIdx.x + j * 256;
    int r = idx >> 6, c = idx & 63;
    T[(size_t)(n0 + r) * 512 + k0 + c] = tile[c][r];
  }
}

// Small-M MFMA GEMM with bf16x3 split (f32-class accuracy).
// MODE 0: plain f32 out [M,512]
// MODE 1: K=1024; k>=512 rows of A come from p0+p1 (summed in staging)
// MODE 2: Q-layout out [b,h,512,64], scaled
// MODE 3: S-layout out [b,h,32,64]
template<int MODE>
__global__ __launch_bounds__(256)
void sgemm_mfma(const float* __restrict__ A0, const float* __restrict__ A1,
                const float* __restrict__ p0, const float* __restrict__ p1,
                const float* __restrict__ W0, const float* __restrict__ W1,
                const float* __restrict__ bias0, const float* __restrict__ bias1,
                float* __restrict__ out0, float* __restrict__ out1,
                float scale, int M, int K)
{
  __shared__ unsigned short Ah[4096], Al[4096], Bh[4096], Bl[4096];
  const int z = blockIdx.z;
  const float* A    = z ? A1 : A0;
  const float* W    = z ? W1 : W0;
  const float* bias = z ? bias1 : bias0;
  float* outf       = z ? out1 : out0;

  const int m0 = blockIdx.x * 64, n0 = blockIdx.y * 64;
  const int tid = threadIdx.x;
  const int lane = tid & 63, wv = tid >> 6, lr = lane & 15, lg = lane >> 4;

  f32x4 acc[4];
  #pragma unroll
  for (int nf = 0; nf < 4; nf++) acc[nf] = (f32x4){0.f, 0.f, 0.f, 0.f};

  for (int k0 = 0; k0 < K; k0 += 64) {
    float4 a0[2], a1[2];
    float bw[2][8];
    const bool dual = (MODE == 1) && (k0 >= 512);
    const int kk = dual ? (k0 - 512) : k0;
    #pragma unroll
    for (int j = 0; j < 2; j++) {
      int idx = tid + j * 256;
      int row = idx >> 3, c8 = idx & 7;
      size_t base = (size_t)(m0 + row) * 512 + kk + c8 * 8;
      if (dual) {
        float4 x0 = *(const float4*)&p0[base];
        float4 x1 = *(const float4*)&p0[base + 4];
        float4 y0 = *(const float4*)&p1[base];
        float4 y1 = *(const float4*)&p1[base + 4];
        a0[j] = (float4){x0.x + y0.x, x0.y + y0.y, x0.z + y0.z, x0.w + y0.w};
        a1[j] = (float4){x1.x + y1.x, x1.y + y1.y, x1.z + y1.z, x1.w + y1.w};
      } else {
        a0[j] = *(const float4*)&A[base];
        a1[j] = *(const float4*)&A[base + 4];
      }
    }
    #pragma unroll
    for (int j = 0; j < 2; j++) {
      int idx = tid + j * 256;
      int nl = idx >> 3, kseg = idx & 7;
      #pragma unroll
      for (int e = 0; e < 8; e++)
        bw[j][e] = W[(size_t)(k0 + kseg * 8 + e) * 512 + n0 + nl];
    }
    __syncthreads();
    #pragma unroll
    for (int j = 0; j < 2; j++) {
      int idx = tid + j * 256;
      int row = idx >> 3, c8 = idx & 7;
      int off = row * 64 + ((c8 * 8) ^ ((row & 7) << 3));
      float v[8] = {a0[j].x, a0[j].y, a0[j].z, a0[j].w,
                    a1[j].x, a1[j].y, a1[j].z, a1[j].w};
      short8 h, l;
      #pragma unroll
      for (int e = 0; e < 8; e++) {
        unsigned short hh = f2b(v[e]);
        h[e] = (short)hh;
        l[e] = (short)f2b(v[e] - b2f(hh));
      }
      *(short8*)&Ah[off] = h;
      *(short8*)&Al[off] = l;
    }
    #pragma unroll
    for (int j = 0; j < 2; j++) {
      int idx = tid + j * 256;
      int nl = idx >> 3, kseg = idx & 7;
      int off = nl * 64 + ((kseg * 8) ^ ((nl & 7) << 3));
      short8 h, l;
      #pragma unroll
      for (int e = 0; e < 8; e++) {
        unsigned short hh = f2b(bw[j][e]);
        h[e] = (short)hh;
        l[e] = (short)f2b(bw[j][e] - b2f(hh));
      }
      *(short8*)&Bh[off] = h;
      *(short8*)&Bl[off] = l;
    }
    __syncthreads();
    #pragma unroll
    for (int ks = 0; ks < 2; ks++) {
      int rowa = wv * 16 + lr;
      int aoff = rowa * 64 + ((ks * 32 + lg * 8) ^ ((rowa & 7) << 3));
      short8 ah = *(const short8*)&Ah[aoff];
      short8 al = *(const short8*)&Al[aoff];
      #pragma unroll
      for (int nf = 0; nf < 4; nf++) {
        int rowb = nf * 16 + lr;
        int boff = rowb * 64 + ((ks * 32 + lg * 8) ^ ((rowb & 7) << 3));
        short8 bh = *(const short8*)&Bh[boff];
        short8 bl = *(const short8*)&Bl[boff];
        acc[nf] = __builtin_amdgcn_mfma_f32_16x16x32_bf16(ah, bh, acc[nf], 0, 0, 0);
        acc[nf] = __builtin_amdgcn_mfma_f32_16x16x32_bf16(ah, bl, acc[nf], 0, 0, 0);
        acc[nf] = __builtin_amdgcn_mfma_f32_16x16x32_bf16(al, bh, acc[nf], 0, 0, 0);
      }
    }
  }

  #pragma unroll
  for (int nf = 0; nf < 4; nf++) {
    int n = n0 + nf * 16 + lr;
    float bv = bias[n];
    #pragma unroll
    for (int i = 0; i < 4; i++) {
      int m = m0 + wv * 16 + lg * 4 + i;
      float v = (acc[nf][i] + bv) * scale;
      if (MODE == 0 || MODE == 1) {
        outf[(size_t)m * 512 + n] = v;
      } else if (MODE == 2) {
        int bb = m >> 9, qq = m & 511, hh = n >> 6, d = n & 63;
        outf[((((size_t)bb * 8 + hh) * 512 + qq) << 6) + d] = v;
      } else {
        int bb = m >> 5, nn = m & 31, hh = n >> 6, d = n & 63;
        outf[((((size_t)bb * 8 + hh) * 32 + nn) << 6) + d] = v;
      }
    }
  }
}

// MFMA projection GEMM, tile 128x128, BK=64, 4 waves x 64x64.
// 1D XCD-grouped grid (1024 blocks): xcd = id&7; the 4 n-blocks sharing an
// A-panel are adjacent on one XCD -> A read from HBM once (was 4x).
// VT=0: out bf16 [b,h,n,t(256),d(64)]  (K path, row-major in d)
// VT=1: out bf16 [b,h,n,d(64),t(256)]  (V path, TRANSPOSED: rows of t per d)
template<int VT>
__global__ __launch_bounds__(256)
void proj_gemm(const float* __restrict__ A,          // [32768,512] f32
               const unsigned short* __restrict__ BT,// [512n][512k] bf16
               const float* __restrict__ bias,       // [512]
               __hip_bfloat16* __restrict__ outW)
{
  __shared__ unsigned short As[128 * 64];
  __shared__ unsigned short Bs[128 * 64];
  const int id = blockIdx.x;
  const int xcd = id & 7, local = id >> 3;       // local 0..127
  const int mx = xcd * 32 + (local >> 2);        // 0..255
  const int ny = local & 3;
  const int m0 = mx * 128, n0 = ny * 128;
  const int tid = threadIdx.x;
  const int lane = tid & 63, wv = tid >> 6, lr = lane & 15, lg = lane >> 4;
  const int wr = wv >> 1, wc = wv & 1;

  f32x4 acc[4][4];
  #pragma unroll
  for (int mi = 0; mi < 4; mi++)
    #pragma unroll
    for (int nj = 0; nj < 4; nj++) acc[mi][nj] = (f32x4){0.f, 0.f, 0.f, 0.f};

  for (int k0 = 0; k0 < 512; k0 += 64) {
    float4 a0[4], a1[4]; uint4 bq[4];
    #pragma unroll
    for (int j = 0; j < 4; j++) {
      int idx = tid + j * 256;
      int row = idx >> 3, c8 = idx & 7;
      const float* ap = A + (size_t)(m0 + row) * 512 + k0 + c8 * 8;
      a0[j] = *(const float4*)ap;
      a1[j] = *(const float4*)(ap + 4);
      bq[j] = *(const uint4*)(BT + (size_t)(n0 + row) * 512 + k0 + c8 * 8);
    }
    __syncthreads();
    #pragma unroll
    for (int j = 0; j < 4; j++) {
      int idx = tid + j * 256;
      int row = idx >> 3, c8 = idx & 7;
      int off = row * 64 + ((c8 * 8) ^ ((row & 7) << 3));
      short8 pk;
      pk[0] = (short)f2b(a0[j].x); pk[1] = (short)f2b(a0[j].y);
      pk[2] = (short)f2b(a0[j].z); pk[3] = (short)f2b(a0[j].w);
      pk[4] = (short)f2b(a1[j].x); pk[5] = (short)f2b(a1[j].y);
      pk[6] = (short)f2b(a1[j].z); pk[7] = (short)f2b(a1[j].w);
      *(short8*)&As[off] = pk;
      *(uint4*)&Bs[off] = bq[j];
    }
    __syncthreads();
    #pragma unroll
    for (int ks = 0; ks < 2; ks++) {
      short8 af[4], bfp[4];
      #pragma unroll
      for (int mi = 0; mi < 4; mi++) {
        int row = wr * 64 + mi * 16 + lr;
        af[mi] = *(const short8*)&As[row * 64 + ((ks * 32 + lg * 8) ^ ((row & 7) << 3))];
      }
      #pragma unroll
      for (int nj = 0; nj < 4; nj++) {
        int row = wc * 64 + nj * 16 + lr;
        bfp[nj] = *(const short8*)&Bs[row * 64 + ((ks * 32 + lg * 8) ^ ((row & 7) << 3))];
      }
      #pragma unroll
      for (int mi = 0; mi < 4; mi++)
        #pragma unroll
        for (int nj = 0; nj < 4; nj++)
          acc[mi][nj] = __builtin_amdgcn_mfma_f32_16x16x32_bf16(af[mi], bfp[nj], acc[mi][nj], 0, 0, 0);
    }
  }

  #pragma unroll
  for (int nj = 0; nj < 4; nj++) {
    int n = n0 + wc * 64 + nj * 16 + lr;
    float bv = bias[n];
    int hh = n >> 6, d = n & 63;
    #pragma unroll
    for (int mi = 0; mi < 4; mi++) {
      if (VT == 0) {
        #pragma unroll
        for (int i = 0; i < 4; i++) {
          int m = m0 + wr * 64 + mi * 16 + lg * 4 + i;
          int bb = m >> 13, r = m & 8191, nn = r >> 8, tt = r & 255;
          outW[(((((size_t)bb * 8 + hh) * 32 + nn) * 256 + tt) << 6) + d] =
              __float2bfloat16(acc[mi][nj][i] + bv);
        }
      } else {
        int m = m0 + wr * 64 + mi * 16 + lg * 4;   // 4 consecutive t
        int bb = m >> 13, r = m & 8191, nn = r >> 8, t0 = r & 255;
        uint2 pk;
        pk.x = (unsigned)f2b(acc[mi][nj][0] + bv) | ((unsigned)f2b(acc[mi][nj][1] + bv) << 16);
        pk.y = (unsigned)f2b(acc[mi][nj][2] + bv) | ((unsigned)f2b(acc[mi][nj][3] + bv) << 16);
        *(uint2*)((unsigned short*)outW +
                  (((((size_t)bb * 8 + hh) * 32 + nn) * 64 + d) << 8) + t0) = pk;
      }
    }
  }
}

// Sentence-level attention: scores over nb=32, softmax, ctx_s; also emits attn_s.
__global__ __launch_bounds__(256)
void sent_attn(const float* __restrict__ qs,   // [b,h,512,64]  (pre-scaled)
               const float* __restrict__ ks,   // [b,h,32,64]
               const float* __restrict__ vs,   // [b,h,32,64]
               float* __restrict__ attn_s,     // [b,h,512,32]
               float* __restrict__ ctx_s)      // [b,512,512]
{
  __shared__ float qsS[32][68];
  __shared__ float ksS[32][68];
  __shared__ float vsS[32][68];
  __shared__ float sS[32][36];
  const int bh = blockIdx.y, b = bh >> 3, h = bh & 7;
  const int q0 = blockIdx.x * 32;
  const int tid = threadIdx.x;

  #pragma unroll
  for (int i = 0; i < 2; i++) {
    int idx = tid + i * 256;
    int r = idx >> 4, c = (idx & 15) * 4;
    *(float4*)&qsS[r][c] = *(const float4*)&qs[((size_t)bh * 512 + q0 + r) * 64 + c];
    *(float4*)&ksS[r][c] = *(const float4*)&ks[((size_t)bh * 32 + r) * 64 + c];
    *(float4*)&vsS[r][c] = *(const float4*)&vs[((size_t)bh * 32 + r) * 64 + c];
  }
  __syncthreads();

  #pragma unroll
  for (int it = 0; it < 4; it++) {
    int pair = tid + it * 256;
    int qq = pair >> 5, nn = pair & 31;
    float s = 0.f;
    #pragma unroll
    for (int k = 0; k < 64; k++) s += qsS[qq][k] * ksS[nn][k];
    sS[qq][nn] = s;
  }
  __syncthreads();

  if (tid < 32) {
    int qq = tid;
    float m = -1e30f;
    #pragma unroll
    for (int n = 0; n < 32; n++) m = fmaxf(m, sS[qq][n]);
    float p[32];
    float sum = 0.f;
    #pragma unroll
    for (int n = 0; n < 32; n++) { p[n] = __expf(sS[qq][n] - m); sum += p[n]; }
    float inv = 1.f / sum;
    #pragma unroll
    for (int n = 0; n < 32; n++) {
      float pv = p[n] * inv;
      sS[qq][n] = pv;
      attn_s[((size_t)bh * 512 + q0 + qq) * 32 + n] = pv;
    }
  }
  __syncthreads();

  #pragma unroll
  for (int it = 0; it < 8; it++) {
    int idx = tid + it * 256;
    int qq = idx >> 6, d = idx & 63;
    float c = 0.f;
    #pragma unroll
    for (int n = 0; n < 32; n++) c += sS[qq][n] * vsS[n][d];
    ctx_s[((size_t)b * 512 + q0 + qq) * 512 + h * 64 + d] = c;
  }
}

// Token-level attention v4 + T5 setprio around MFMA clusters (2 independent
// blocks/CU -> non-lockstep, the regime where setprio pays on attention).
__global__ __launch_bounds__(256, 2)
void tok_attn_v4(const float* __restrict__ qw,            // [b,h,512,64] f32 pre-scaled
                 const __hip_bfloat16* __restrict__ kw,   // [b,h,32,256,64]
                 const __hip_bfloat16* __restrict__ vwT,  // [b,h,32,64,256] TRANSPOSED
                 const float* __restrict__ attn_s,        // [b,h,512,32]
                 float* __restrict__ part0,
                 float* __restrict__ part1)
{
  __shared__ unsigned short kvbuf[18432];    // K [256][72]  OR  Vt [64][264]
  __shared__ unsigned short pbuf[64 * 264];  // P [64 q-rows][256 t + 8 pad]
  const int bid = blockIdx.x;
  const int xcd = bid & 7, slot = bid >> 3;
  const int bh = xcd * 4 + (slot >> 4);
  const int rest = slot & 15;
  const int qt = rest >> 1, z = rest & 1;
  const int b = bh >> 3, h = bh & 7;
  const int tid = threadIdx.x;
  const int wv = tid >> 6, lane = tid & 63, lg = lane >> 4, lr = lane & 15;
  const int qbase = qt * 64 + wv * 16;
  const int n0 = z * 16;
  const int vd = wv * 16 + (lane >> 2), tq = lane & 3;

  short8 qfrag[2];
  {
    const float* qrow = qw + ((size_t)bh * 512 + qbase + lr) * 64;
    #pragma unroll
    for (int ks = 0; ks < 2; ks++) {
      float4 u0 = *(const float4*)&qrow[ks * 32 + lg * 8];
      float4 u1 = *(const float4*)&qrow[ks * 32 + lg * 8 + 4];
      short8 t;
      t[0] = f2b(u0.x); t[1] = f2b(u0.y); t[2] = f2b(u0.z); t[3] = f2b(u0.w);
      t[4] = f2b(u1.x); t[5] = f2b(u1.y); t[6] = f2b(u1.z); t[7] = f2b(u1.w);
      qfrag[ks] = t;
    }
  }
  float asv[16];
  {
    const float* ap = attn_s + ((size_t)bh * 512 + qbase + lr) * 32 + n0;
    #pragma unroll
    for (int i = 0; i < 4; i++) {
      float4 u = *(const float4*)&ap[i * 4];
      asv[i * 4 + 0] = u.x; asv[i * 4 + 1] = u.y;
      asv[i * 4 + 2] = u.z; asv[i * 4 + 3] = u.w;
    }
  }

  f32x4 acc[4];
  #pragma unroll
  for (int dt = 0; dt < 4; dt++) acc[dt] = (f32x4){0.f, 0.f, 0.f, 0.f};

  const unsigned short* kwb = (const unsigned short*)kw + (size_t)bh * 32 * 256 * 64;
  const unsigned short* vtb = (const unsigned short*)vwT + (size_t)bh * 32 * 64 * 256;
  const unsigned int pbase = (wv * 16 + lr) * 264;

  for (int ni = 0; ni < 16; ni++) {
    const int n = n0 + ni;
    __syncthreads();   // prior PV done reading kvbuf
    {  // stage K: one row per thread, immediate global->reg->LDS
      const unsigned short* ksrc = kwb + ((size_t)n * 256 + tid) * 64;
      uint4 r[8];
      #pragma unroll
      for (int j = 0; j < 8; j++) r[j] = *(const uint4*)(ksrc + j * 8);
      #pragma unroll
      for (int j = 0; j < 8; j++) *(uint4*)&kvbuf[tid * 72 + j * 8] = r[j];
    }
    __syncthreads();

    // QK: Sᵀ[t][q] via mfma(K, Q)
    f32x4 sfr[16];
    #pragma unroll
    for (int tt = 0; tt < 16; tt++) sfr[tt] = (f32x4){0.f, 0.f, 0.f, 0.f};
    __builtin_amdgcn_s_setprio(1);
    #pragma unroll
    for (int tt = 0; tt < 16; tt++) {
      #pragma unroll
      for (int ks = 0; ks < 2; ks++) {
        short8 kf = *(const short8*)&kvbuf[(16 * tt + lr) * 72 + ks * 32 + lg * 8];
        sfr[tt] = __builtin_amdgcn_mfma_f32_16x16x32_bf16(kf, qfrag[ks], sfr[tt], 0, 0, 0);
      }
    }
    __builtin_amdgcn_s_setprio(0);
    // softmax (shift-free) + sentence weighting for q = qbase+lr
    float lsum = 0.f;
    #pragma unroll
    for (int tt = 0; tt < 16; tt++) {
      #pragma unroll
      for (int i = 0; i < 4; i++) {
        float e = __expf(sfr[tt][i]);
        sfr[tt][i] = e;
        lsum += e;
      }
    }
    lsum += __shfl_xor(lsum, 16);
    lsum += __shfl_xor(lsum, 32);
    const float coef = asv[ni] / lsum;
    #pragma unroll
    for (int tt = 0; tt < 16; tt++) {
      uint2 pk;
      pk.x = (unsigned)f2b(sfr[tt][0] * coef) | ((unsigned)f2b(sfr[tt][1] * coef) << 16);
      pk.y = (unsigned)f2b(sfr[tt][2] * coef) | ((unsigned)f2b(sfr[tt][3] * coef) << 16);
      *(uint2*)&pbuf[pbase + tt * 16 + lg * 4] = pk;
    }
    __syncthreads();   // all QK reads of kvbuf done

    {  // stage V from vwT: b128 rows, j^tq swizzle, immediate global->reg->LDS
      const unsigned short* vsrc = vtb + ((size_t)n * 64 + vd) * 256 + tq * 64;
      uint4 r[8];
      #pragma unroll
      for (int j = 0; j < 8; j++) r[j] = *(const uint4*)(vsrc + j * 8);
      #pragma unroll
      for (int j = 0; j < 8; j++)
        *(uint4*)&kvbuf[vd * 264 + tq * 64 + ((j ^ tq) * 8)] = r[j];
    }
    __syncthreads();

    // PV: acc[q][d] += P[q][t] * V[t][d]
    __builtin_amdgcn_s_setprio(1);
    #pragma unroll
    for (int ks = 0; ks < 8; ks++) {
      short8 pa = *(const short8*)&pbuf[pbase + ks * 32 + lg * 8];
      const int tqe = ks >> 1, joff = (ks & 1) * 4 + lg;
      #pragma unroll
      for (int dt = 0; dt < 4; dt++) {
        short8 vb = *(const short8*)&kvbuf[(16 * dt + lr) * 264 + tqe * 64 + ((joff ^ tqe) * 8)];
        acc[dt] = __builtin_amdgcn_mfma_f32_16x16x32_bf16(pa, vb, acc[dt], 0, 0, 0);
      }
    }
    __builtin_amdgcn_s_setprio(0);
  }

  float* pout = z ? part1 : part0;
  #pragma unroll
  for (int dt = 0; dt < 4; dt++) {
    #pragma unroll
    for (int i = 0; i < 4; i++) {
      int qg = qt * 64 + wv * 16 + lg * 4 + i;
      pout[((size_t)b * 512 + qg) * 512 + h * 64 + dt * 16 + lr] = acc[dt][i];
    }
  }
}

extern "C" void kernel_launch(void* const* d_in, const int* in_sizes, int n_in,
                              void* d_out, int out_size, void* d_ws, size_t ws_size,
                              hipStream_t stream)
{
  (void)in_sizes; (void)n_in; (void)out_size; (void)ws_size;
  const float* q    = (const float*)d_in[0];
  const float* k_w  = (const float*)d_in[1];
  const float* v_w  = (const float*)d_in[2];
  const float* k_s  = (const float*)d_in[3];
  const float* v_s  = (const float*)d_in[4];
  const float* W_qs = (const float*)d_in[5];  const float* b_qs = (const float*)d_in[6];
  const float* W_ks = (const float*)d_in[7];  const float* b_ks = (const float*)d_in[8];
  const float* W_vs = (const float*)d_in[9];  const float* b_vs = (const float*)d_in[10];
  const float* W_qw = (const float*)d_in[11]; const float* b_qw = (const float*)d_in[12];
  const float* W_kw = (const float*)d_in[13]; const float* b_kw = (const float*)d_in[14];
  const float* W_vw = (const float*)d_in[15]; const float* b_vw = (const float*)d_in[16];
  const float* W_fc1= (const float*)d_in[17]; const float* b_fc1= (const float*)d_in[18];
  const float* W_fc = (const float*)d_in[19]; const float* b_fc = (const float*)d_in[20];
  float* out = (float*)d_out;

  char* ws = (char*)d_ws;
  const size_t MB = 1ull << 20;
  const size_t KB = 1ull << 10;
  float* qs_ws    = (float*)(ws + 0 * MB);       // [b,h,512,64] 4 MB (dead after sent_attn)
  float* qw_ws    = (float*)(ws + 4 * MB);       // [b,h,512,64] 4 MB
  float* ks_ws    = (float*)(ws + 8 * MB);       // [b,h,32,64] 256 KB
  unsigned short* WkT = (unsigned short*)(ws + 8 * MB + 512 * KB);  // 512 KB
  float* vs_ws    = (float*)(ws + 9 * MB);       // [b,h,32,64] 256 KB
  unsigned short* WvT = (unsigned short*)(ws + 9 * MB + 512 * KB);  // 512 KB
  float* attns_ws = (float*)(ws + 10 * MB);      // [b,h,512,32] 2 MB
  float* ctxs_ws  = (float*)(ws + 12 * MB);      // [b,512,512] 4 MB (dead after fc1 gemm)
  float* ctxsf_ws = (float*)(ws + 16 * MB);      // [b,512,512] 4 MB
  __hip_bfloat16* kw_ws  = (__hip_bfloat16*)(ws + 24 * MB);  // [b,h,32,256,64] 32 MB
  __hip_bfloat16* vwT_ws = (__hip_bfloat16*)(ws + 56 * MB);  // [b,h,32,64,256] 32 MB
  float* part0 = (float*)(ws + 0 * MB);          // over qs_ws   (4 MB)
  float* part1 = (float*)(ws + 12 * MB);         // over ctxs_ws (4 MB)

  dim3 blk(256);
  // weight transpose-casts for the MFMA projections
  wcast_t<<<dim3(8, 8, 2), blk, 0, stream>>>(W_kw, WkT, W_vw, WvT);
  // small projections (MFMA, bf16x3 split): qs+qw fused, ks+vs fused
  sgemm_mfma<2><<<dim3(32, 8, 2), blk, 0, stream>>>(
      q, q, nullptr, nullptr, W_qs, W_qw, b_qs, b_qw, qs_ws, qw_ws, SCALE_F, 2048, 512);
  sgemm_mfma<3><<<dim3(2, 8, 2), blk, 0, stream>>>(
      k_s, v_s, nullptr, nullptr, W_ks, W_vs, b_ks, b_vs, ks_ws, vs_ws, 1.f, 128, 512);
  // big projections (MFMA, XCD-grouped 1D grid for A L2-reuse)
  proj_gemm<0><<<dim3(1024), blk, 0, stream>>>(k_w, WkT, b_kw, kw_ws);
  proj_gemm<1><<<dim3(1024), blk, 0, stream>>>(v_w, WvT, b_vw, vwT_ws);
  // sentence attention (+ attn_s for token level)
  sent_attn<<<dim3(16, 32), blk, 0, stream>>>(qs_ws, ks_ws, vs_ws, attns_ws, ctxs_ws);
  // ctx_s @ W_fc1
  sgemm_mfma<0><<<dim3(32, 8, 1), blk, 0, stream>>>(
      ctxs_ws, ctxs_ws, nullptr, nullptr, W_fc1, W_fc1, b_fc1, b_fc1,
      ctxsf_ws, ctxsf_ws, 1.f, 2048, 512);
  // token attention v4 (staged, XCD-grouped, setprio) -> partials
  tok_attn_v4<<<dim3(512), blk, 0, stream>>>(qw_ws, kw_ws, vwT_ws, attns_ws, part0, part1);
  // final combine: concat([ctx_s_fc1, part0+part1]) @ W_fc + b_fc
  sgemm_mfma<1><<<dim3(32, 8, 1), blk, 0, stream>>>(
      ctxsf_ws, ctxsf_ws, part0, part1, W_fc, W_fc, b_fc, b_fc,
      out, out, 1.f, 2048, 1024);
}